// Round 4
// baseline (1121.061 us; speedup 1.0000x reference)
//
#include <hip/hip_runtime.h>
#include <math.h>

#define H 16
#define NF 64
#define TPB 256
#define BITEMS 10   // k_bscan capacity: 256*10=2560 buckets >= 2344

__device__ __forceinline__ float lrelu(float v){ return v > 0.f ? v : 0.2f*v; }

// ---- derived edge-attention weights: par[0..1] = We1@ae1, par[2..3] = We2@ae2 ----
__global__ void k_prep(const float* __restrict__ We1, const float* __restrict__ ae1,
                       const float* __restrict__ We2, const float* __restrict__ ae2,
                       float* __restrict__ params){
  int t = threadIdx.x;
  if (t < 4){
    const float* We = (t < 2) ? We1 : We2;
    const float* ae = (t < 2) ? ae1 : ae2;
    int r = t & 1;
    float s = 0.f;
    for (int c = 0; c < H; ++c) s += We[r*H + c] * ae[c];
    params[t] = s;
  }
}

// ---- bucket histogram: bucket = 64 consecutive dst nodes; counters padded to 1/line ----
__global__ __launch_bounds__(TPB) void k_bhist(const int* __restrict__ dst,
                                               int* __restrict__ bcnt, int E){
  int e = blockIdx.x*TPB + threadIdx.x;
  if (e >= E) return;
  atomicAdd(&bcnt[(dst[e] >> 6) * 16], 1);
}

// ---- single-block exclusive scan of bucket counts -> bbase (== rowptr chunk bases) ----
__global__ __launch_bounds__(256) void k_bscan(const int* __restrict__ bcnt,
    int* __restrict__ bbase, int* __restrict__ rowptr, int B, int N, int E){
  __shared__ int sh[256];
  int t = threadIdx.x;
  int base = t*BITEMS;
  int loc[BITEMS]; int s = 0;
  for (int i = 0; i < BITEMS; ++i){
    int idx = base + i;
    loc[i] = s;
    s += (idx < B) ? bcnt[idx*16] : 0;
  }
  sh[t] = s; __syncthreads();
  for (int off = 1; off < 256; off <<= 1){
    int add = (t >= off) ? sh[t-off] : 0;
    __syncthreads();
    sh[t] += add;
    __syncthreads();
  }
  int toff = sh[t] - s;
  for (int i = 0; i < BITEMS; ++i){
    int idx = base + i;
    if (idx < B) bbase[idx] = toff + loc[i];
  }
  if (t == 0){ bbase[B] = E; rowptr[N] = E; }
}

// ---- bin edges into bucket regions; write frontier = ~2344 lines (L2-resident) ----
__global__ __launch_bounds__(TPB) void k_bin(const int* __restrict__ src, const int* __restrict__ dst,
    const float* __restrict__ attr, const float* __restrict__ wp,
    const int* __restrict__ bbase, int* __restrict__ bcur,
    int4* __restrict__ binned, int E){
  int e = blockIdx.x*TPB + threadIdx.x;
  if (e >= E) return;
  int d = dst[e];
  int b = d >> 6;
  float2 a = ((const float2*)attr)[e];
  float d1 = a.x*wp[0] + a.y*wp[1];
  float d2 = a.x*wp[2] + a.y*wp[3];
  int pos = bbase[b] + atomicAdd(&bcur[b*16], 1);
  binned[pos] = make_int4(src[e], d, __float_as_int(d1), __float_as_int(d2));
}

// ---- per-bucket CSR: LDS histogram + wave scan -> rowptr; LDS-cursor scatter ----
__global__ __launch_bounds__(256) void k_csr(const int4* __restrict__ binned,
    const int* __restrict__ bbase, int* __restrict__ rowptr,
    int* __restrict__ csr_src, float* __restrict__ dotA, float* __restrict__ dotB, int N){
  __shared__ int lcnt[64];
  __shared__ int lcur[64];
  __shared__ int sr[2];
  int b = blockIdx.x;
  int t = threadIdx.x;
  int node0 = b << 6;
  if (t < 2) sr[t] = bbase[b + t];
  if (t < 64) lcnt[t] = 0;
  __syncthreads();
  int r0 = sr[0], r1 = sr[1];
  for (int i = r0 + t; i < r1; i += 256){
    int4 rec = binned[i];
    atomicAdd(&lcnt[rec.y - node0], 1);
  }
  __syncthreads();
  if (t < 64){                       // threads 0..63 == wave 0: shfl-scan is safe
    int v = lcnt[t];
    int x = v;
    for (int o = 1; o < 64; o <<= 1){
      int y = __shfl_up(x, o);
      if (t >= o) x += y;
    }
    int excl = x - v;
    lcur[t] = excl;
    if (node0 + t < N) rowptr[node0 + t] = r0 + excl;
  }
  __syncthreads();
  for (int i = r0 + t; i < r1; i += 256){
    int4 rec = binned[i];
    int pos = r0 + atomicAdd(&lcur[rec.y - node0], 1);
    csr_src[pos] = rec.x;
    dotA[pos] = __int_as_float(rec.z);
    dotB[pos] = __int_as_float(rec.w);
  }
}

// ---- layer-1 node transform: h = x @ W1, alpha_src/dst ----
__global__ __launch_bounds__(TPB) void k_node1(const float* __restrict__ x, const float* __restrict__ W,
    const float* __restrict__ av_s, const float* __restrict__ av_d,
    float* __restrict__ hout, float* __restrict__ asn, float* __restrict__ adn, int N){
  __shared__ float sW[NF*H];
  __shared__ float sas[H], sad[H];
  int t = threadIdx.x;
  for (int i = t; i < NF*H; i += TPB) sW[i] = W[i];
  if (t < H){ sas[t] = av_s[t]; sad[t] = av_d[t]; }
  __syncthreads();
  int n = blockIdx.x*TPB + t;
  if (n >= N) return;
  float h[H];
  #pragma unroll
  for (int j = 0; j < H; ++j) h[j] = 0.f;
  const float4* xr = (const float4*)(x + (size_t)n*NF);
  #pragma unroll
  for (int k4 = 0; k4 < NF/4; ++k4){
    float4 xv = xr[k4];
    #pragma unroll
    for (int j = 0; j < H; ++j){
      h[j] += xv.x*sW[(4*k4+0)*H+j] + xv.y*sW[(4*k4+1)*H+j]
            + xv.z*sW[(4*k4+2)*H+j] + xv.w*sW[(4*k4+3)*H+j];
    }
  }
  float4* ho = (float4*)(hout + (size_t)n*H);
  ho[0] = make_float4(h[0],h[1],h[2],h[3]);
  ho[1] = make_float4(h[4],h[5],h[6],h[7]);
  ho[2] = make_float4(h[8],h[9],h[10],h[11]);
  ho[3] = make_float4(h[12],h[13],h[14],h[15]);
  float ss = 0.f, sd = 0.f;
  #pragma unroll
  for (int j = 0; j < H; ++j){ ss += h[j]*sas[j]; sd += h[j]*sad[j]; }
  asn[n] = ss; adn[n] = sd;
}

// ---- fused GAT aggregation: denom + numerator + self-loop + bias + relu, no atomics ----
__global__ __launch_bounds__(TPB) void k_gat(const int* __restrict__ rowptr,
    const int* __restrict__ csr_src, const float* __restrict__ dot,
    const float* __restrict__ asn, const float* __restrict__ adn,
    const float* __restrict__ h, const float* __restrict__ bias,
    float* __restrict__ out, int N){
  int t = threadIdx.x;
  int lane = t & (H-1);
  int n = blockIdx.x*(TPB/H) + (t >> 4);
  if (n >= N) return;
  int r0 = rowptr[n], r1 = rowptr[n+1];
  float adn_n = adn[n];
  float den = 0.f, acc = 0.f, sd = 0.f;
  int i = r0;
  for (; i + 4 <= r1; i += 4){
    int s0 = csr_src[i+0], s1 = csr_src[i+1], s2 = csr_src[i+2], s3 = csr_src[i+3];
    float d0 = dot[i+0], d1 = dot[i+1], d2 = dot[i+2], d3 = dot[i+3];
    float a0 = asn[s0], a1 = asn[s1], a2 = asn[s2], a3 = asn[s3];
    float h0 = h[(size_t)s0*H+lane], h1 = h[(size_t)s1*H+lane],
          h2 = h[(size_t)s2*H+lane], h3 = h[(size_t)s3*H+lane];
    float w0 = __expf(lrelu(a0 + adn_n + d0));
    float w1 = __expf(lrelu(a1 + adn_n + d1));
    float w2 = __expf(lrelu(a2 + adn_n + d2));
    float w3 = __expf(lrelu(a3 + adn_n + d3));
    den += (w0 + w1) + (w2 + w3);
    sd  += (d0 + d1) + (d2 + d3);
    acc += (w0*h0 + w1*h1) + (w2*h2 + w3*h3);
  }
  for (; i < r1; ++i){
    int s = csr_src[i];
    float d = dot[i];
    float w = __expf(lrelu(asn[s] + adn_n + d));
    den += w; sd += d;
    acc += w * h[(size_t)s*H + lane];
  }
  // self-loop: edge_attr = mean of incoming attr -> dot = mean of incoming dots (linear)
  float cntf = (float)(r1 - r0);
  float lael = sd / fmaxf(cntf, 1.f);
  float wl = __expf(lrelu(asn[n] + adn_n + lael));
  den += wl;
  acc += wl * h[(size_t)n*H + lane];
  out[(size_t)n*H + lane] = fmaxf(acc/(den + 1e-16f) + bias[lane], 0.f);
}

// ---- BN sum/sumsq: per-block partials, zero global atomics ----
__global__ __launch_bounds__(TPB) void k_stats(const float* __restrict__ B,
    float* __restrict__ partial, int N){
  __shared__ float lds[4][32];
  int t = threadIdx.x;
  int n = blockIdx.x*TPB + t;
  float v[H];
  if (n < N){
    const float4* br = (const float4*)(B + (size_t)n*H);
    float4 a0 = br[0], a1 = br[1], a2 = br[2], a3 = br[3];
    v[0]=a0.x; v[1]=a0.y; v[2]=a0.z; v[3]=a0.w;
    v[4]=a1.x; v[5]=a1.y; v[6]=a1.z; v[7]=a1.w;
    v[8]=a2.x; v[9]=a2.y; v[10]=a2.z; v[11]=a2.w;
    v[12]=a3.x; v[13]=a3.y; v[14]=a3.z; v[15]=a3.w;
  } else {
    #pragma unroll
    for (int f = 0; f < H; ++f) v[f] = 0.f;
  }
  float s[H], q[H];
  #pragma unroll
  for (int f = 0; f < H; ++f){ s[f] = v[f]; q[f] = v[f]*v[f]; }
  for (int m = 1; m < 64; m <<= 1){
    #pragma unroll
    for (int f = 0; f < H; ++f){
      s[f] += __shfl_xor(s[f], m);
      q[f] += __shfl_xor(q[f], m);
    }
  }
  int wave = t >> 6, lane = t & 63;
  if (lane == 0){
    #pragma unroll
    for (int f = 0; f < H; ++f){ lds[wave][f] = s[f]; lds[wave][H+f] = q[f]; }
  }
  __syncthreads();
  if (t < 32)
    partial[(size_t)blockIdx.x*32 + t] = lds[0][t] + lds[1][t] + lds[2][t] + lds[3][t];
}

// ---- final BN reduction over block partials + scale/shift ----
__global__ __launch_bounds__(256) void k_bnprep(const float* __restrict__ partial, int nb,
    const float* __restrict__ gamma, const float* __restrict__ beta,
    float* __restrict__ scale, float* __restrict__ shift, int N){
  __shared__ float red[256];
  __shared__ float tot[32];
  int t = threadIdx.x;
  int f = t & 31, c = t >> 5;        // 8 chunks x 32 features
  float s = 0.f;
  for (int b = c; b < nb; b += 8) s += partial[(size_t)b*32 + f];
  red[c*32 + f] = s;
  __syncthreads();
  if (t < 32){
    float S = 0.f;
    #pragma unroll
    for (int cc = 0; cc < 8; ++cc) S += red[cc*32 + t];
    tot[t] = S;
  }
  __syncthreads();
  if (t < H){
    float inv = 1.f / (float)N;
    float mu  = tot[t] * inv;
    float var = tot[H+t] * inv - mu*mu;
    float sc  = gamma[t] * rsqrtf(var + 1e-5f);
    scale[t] = sc;
    shift[t] = beta[t] - mu*sc;
  }
}

// ---- layer-2 node transform: BN + h = xn @ W2 + alphas ----
__global__ __launch_bounds__(TPB) void k_node2(const float* __restrict__ Bin, const float* __restrict__ scale,
    const float* __restrict__ shift, const float* __restrict__ W,
    const float* __restrict__ av_s, const float* __restrict__ av_d,
    float* __restrict__ hout, float* __restrict__ asn, float* __restrict__ adn, int N){
  __shared__ float sW[H*H];
  __shared__ float ssc[H], ssh[H], sas[H], sad[H];
  int t = threadIdx.x;
  if (t < H*H) sW[t] = W[t];
  if (t < H){ ssc[t] = scale[t]; ssh[t] = shift[t]; sas[t] = av_s[t]; sad[t] = av_d[t]; }
  __syncthreads();
  int n = blockIdx.x*TPB + t;
  if (n >= N) return;
  const float4* br = (const float4*)(Bin + (size_t)n*H);
  float4 a0 = br[0], a1 = br[1], a2 = br[2], a3 = br[3];
  float xn[H] = {a0.x,a0.y,a0.z,a0.w, a1.x,a1.y,a1.z,a1.w,
                 a2.x,a2.y,a2.z,a2.w, a3.x,a3.y,a3.z,a3.w};
  #pragma unroll
  for (int f = 0; f < H; ++f) xn[f] = xn[f]*ssc[f] + ssh[f];
  float h[H];
  #pragma unroll
  for (int j = 0; j < H; ++j) h[j] = 0.f;
  #pragma unroll
  for (int k = 0; k < H; ++k){
    float xv = xn[k];
    #pragma unroll
    for (int j = 0; j < H; ++j) h[j] += xv * sW[k*H+j];
  }
  float4* ho = (float4*)(hout + (size_t)n*H);
  ho[0] = make_float4(h[0],h[1],h[2],h[3]);
  ho[1] = make_float4(h[4],h[5],h[6],h[7]);
  ho[2] = make_float4(h[8],h[9],h[10],h[11]);
  ho[3] = make_float4(h[12],h[13],h[14],h[15]);
  float ss = 0.f, sd = 0.f;
  #pragma unroll
  for (int j = 0; j < H; ++j){ ss += h[j]*sas[j]; sd += h[j]*sad[j]; }
  asn[n] = ss; adn[n] = sd;
}

// ---- mean-pool accumulation; batch is sorted -> wave-uniform fast path ----
__global__ __launch_bounds__(TPB) void k_pool(const float* __restrict__ B,
    const int* __restrict__ batch, float* __restrict__ pooled, float* __restrict__ gcnt, int N){
  int n = blockIdx.x*TPB + threadIdx.x;
  int lane = threadIdx.x & 63;
  bool valid = n < N;
  int g = valid ? batch[n] : -1;
  float v[H];
  if (valid){
    const float4* br = (const float4*)(B + (size_t)n*H);
    float4 a0 = br[0], a1 = br[1], a2 = br[2], a3 = br[3];
    v[0]=a0.x; v[1]=a0.y; v[2]=a0.z; v[3]=a0.w;
    v[4]=a1.x; v[5]=a1.y; v[6]=a1.z; v[7]=a1.w;
    v[8]=a2.x; v[9]=a2.y; v[10]=a2.z; v[11]=a2.w;
    v[12]=a3.x; v[13]=a3.y; v[14]=a3.z; v[15]=a3.w;
  } else {
    #pragma unroll
    for (int f = 0; f < H; ++f) v[f] = 0.f;
  }
  int g0 = __shfl(g, 0);
  bool allsame = __all(valid && g == g0);
  if (allsame){
    float s[H];
    #pragma unroll
    for (int f = 0; f < H; ++f) s[f] = v[f];
    for (int m = 1; m < 64; m <<= 1){
      #pragma unroll
      for (int f = 0; f < H; ++f) s[f] += __shfl_xor(s[f], m);
    }
    if (lane == 0){
      float* p = pooled + (size_t)g0*H;
      #pragma unroll
      for (int f = 0; f < H; ++f) atomicAdd(&p[f], s[f]);
      atomicAdd(&gcnt[g0], 64.f);
    }
  } else if (valid){
    float* p = pooled + (size_t)g*H;
    #pragma unroll
    for (int f = 0; f < H; ++f) atomicAdd(&p[f], v[f]);
    atomicAdd(&gcnt[g], 1.f);
  }
}

// ---- D2RL head: one block of 512 threads (one per graph) ----
__device__ void block_stats16(const float* v, float* mu, float* rs,
                              float* wsum, float* wsq, int G){
  float s[H], q[H];
  #pragma unroll
  for (int f = 0; f < H; ++f){ s[f] = v[f]; q[f] = v[f]*v[f]; }
  for (int m = 1; m < 64; m <<= 1){
    #pragma unroll
    for (int f = 0; f < H; ++f){
      s[f] += __shfl_xor(s[f], m);
      q[f] += __shfl_xor(q[f], m);
    }
  }
  int wave = threadIdx.x >> 6, lane = threadIdx.x & 63;
  if (lane == 0){
    #pragma unroll
    for (int f = 0; f < H; ++f){ wsum[wave*H+f] = s[f]; wsq[wave*H+f] = q[f]; }
  }
  __syncthreads();
  int t = threadIdx.x;
  if (t < H){
    float S = 0.f, Q = 0.f;
    for (int w = 0; w < 8; ++w){ S += wsum[w*H+t]; Q += wsq[w*H+t]; }
    float m_ = S / (float)G;
    float var = Q / (float)G - m_*m_;
    mu[t] = m_;
    rs[t] = rsqrtf(var + 1e-5f);
  }
  __syncthreads();
}

__global__ __launch_bounds__(512) void k_head(const float* __restrict__ pooled, const float* __restrict__ gcnt,
    const float* __restrict__ g1, const float* __restrict__ be1,
    const float* __restrict__ Wl1, const float* __restrict__ bl1,
    const float* __restrict__ g2, const float* __restrict__ be2,
    const float* __restrict__ Wl2, const float* __restrict__ bl2,
    const float* __restrict__ g3, const float* __restrict__ be3,
    const float* __restrict__ Wl3, const float* __restrict__ bl3,
    const float* __restrict__ Wo, const float* __restrict__ bo,
    float* __restrict__ out, int G){
  __shared__ float wsum[8*H], wsq[8*H];
  __shared__ float pmu[H], prs[H], smu[H], srs[H];
  int g = threadIdx.x;
  float p[H];
  if (g < G){
    float c = fmaxf(gcnt[g], 1.f);
    #pragma unroll
    for (int f = 0; f < H; ++f) p[f] = pooled[(size_t)g*H+f] / c;
  } else {
    #pragma unroll
    for (int f = 0; f < H; ++f) p[f] = 0.f;
  }
  block_stats16(p, pmu, prs, wsum, wsq, G);
  float xn[H], z[H];
  #pragma unroll
  for (int f = 0; f < H; ++f) xn[f] = g1[f]*(p[f]-pmu[f])*prs[f] + be1[f];
  #pragma unroll
  for (int j = 0; j < H; ++j) z[j] = bl1[j];
  for (int k = 0; k < H; ++k){
    float xv = xn[k];
    #pragma unroll
    for (int j = 0; j < H; ++j) z[j] += xv * Wl1[k*H+j];
  }
  #pragma unroll
  for (int j = 0; j < H; ++j) z[j] = fmaxf(z[j], 0.f);
  block_stats16(z, smu, srs, wsum, wsq, G);
  float x2[2*H], z2[H];
  #pragma unroll
  for (int f = 0; f < H; ++f){
    x2[f]   = g2[f]  *(z[f]-smu[f])*srs[f] + be2[f];
    x2[H+f] = g2[H+f]*(p[f]-pmu[f])*prs[f] + be2[H+f];
  }
  #pragma unroll
  for (int j = 0; j < H; ++j) z2[j] = bl2[j];
  for (int k = 0; k < 2*H; ++k){
    float xv = x2[k];
    #pragma unroll
    for (int j = 0; j < H; ++j) z2[j] += xv * Wl2[k*H+j];
  }
  #pragma unroll
  for (int j = 0; j < H; ++j) z2[j] = fmaxf(z2[j], 0.f);
  block_stats16(z2, smu, srs, wsum, wsq, G);
  float x3[2*H], z3[H];
  #pragma unroll
  for (int f = 0; f < H; ++f){
    x3[f]   = g3[f]  *(z2[f]-smu[f])*srs[f] + be3[f];
    x3[H+f] = g3[H+f]*(p[f]-pmu[f])*prs[f] + be3[H+f];
  }
  #pragma unroll
  for (int j = 0; j < H; ++j) z3[j] = bl3[j];
  for (int k = 0; k < 2*H; ++k){
    float xv = x3[k];
    #pragma unroll
    for (int j = 0; j < H; ++j) z3[j] += xv * Wl3[k*H+j];
  }
  #pragma unroll
  for (int j = 0; j < H; ++j) z3[j] = fmaxf(z3[j], 0.f);
  if (g < G){
    float o = bo[0];
    #pragma unroll
    for (int j = 0; j < H; ++j) o += z3[j]*Wo[j];
    out[g] = o;
  }
}

extern "C" void kernel_launch(void* const* d_in, const int* in_sizes, int n_in,
                              void* d_out, int out_size, void* d_ws, size_t ws_size,
                              hipStream_t stream) {
  const float* x     = (const float*)d_in[0];
  const int*   ei    = (const int*)d_in[1];
  const float* attr  = (const float*)d_in[2];
  const int*   batch = (const int*)d_in[3];
  const float* W1  = (const float*)d_in[4];
  const float* We1 = (const float*)d_in[5];
  const float* as1 = (const float*)d_in[6];
  const float* ad1 = (const float*)d_in[7];
  const float* ae1 = (const float*)d_in[8];
  const float* b1  = (const float*)d_in[9];
  const float* bn1g = (const float*)d_in[10];
  const float* bn1b = (const float*)d_in[11];
  const float* W2  = (const float*)d_in[12];
  const float* We2 = (const float*)d_in[13];
  const float* as2 = (const float*)d_in[14];
  const float* ad2 = (const float*)d_in[15];
  const float* ae2 = (const float*)d_in[16];
  const float* b2  = (const float*)d_in[17];
  const float* bnl1g = (const float*)d_in[18];
  const float* bnl1b = (const float*)d_in[19];
  const float* Wl1 = (const float*)d_in[20];
  const float* bl1 = (const float*)d_in[21];
  const float* bnl2g = (const float*)d_in[22];
  const float* bnl2b = (const float*)d_in[23];
  const float* Wl2 = (const float*)d_in[24];
  const float* bl2 = (const float*)d_in[25];
  const float* bnl3g = (const float*)d_in[26];
  const float* bnl3b = (const float*)d_in[27];
  const float* Wl3 = (const float*)d_in[28];
  const float* bl3 = (const float*)d_in[29];
  const float* Wo  = (const float*)d_in[30];
  const float* bo  = (const float*)d_in[31];

  int N = in_sizes[0] / NF;
  int E = in_sizes[1] / 2;
  int G = out_size;
  const int* srcp = ei;
  const int* dstp = ei + E;

  int B    = (N + 63) >> 6;                          // buckets of 64 dst nodes (2344)
  int nbE  = (E + TPB - 1)/TPB;
  int nbN  = (N + TPB - 1)/TPB;
  int nbG  = (N + (TPB/H) - 1)/(TPB/H);              // k_gat blocks (16 nodes/block)

  // ---- workspace layout ----
  // binned (16B * E) is dead after k_csr; A/Bv/asn/adn alias on top of it.
  char* wsb = (char*)d_ws;
  int4*  binned = (int4*)wsb;                        // [0, 16E)
  float* A   = (float*)wsb;                          // 16N floats   (alias, used post-CSR)
  float* Bv  = A  + (size_t)16*N;                    // 16N floats
  float* asn = Bv + (size_t)16*N;                    // N
  float* adn = asn + N;                              // N   (34N*4 = 20.4MB <= 16E = 76.8MB)
  char* p = wsb + (size_t)16*E;
  int*   csr_src = (int*)p;   p += (size_t)4*E;
  float* dotA    = (float*)p; p += (size_t)4*E;
  float* dotB    = (float*)p; p += (size_t)4*E;
  int*   rowptr  = (int*)p;   p += (size_t)4*(N+1);
  int*   bbase   = (int*)p;   p += (size_t)4*(B+1);
  int*   bcnt    = (int*)p;   p += (size_t)64*B;     // padded: 1 counter per 64B line
  int*   bcur    = (int*)p;   p += (size_t)64*B;
  float* par     = (float*)p; p += 4*64;             // [0..3]=wp [4..19]=scale [20..35]=shift
  float* pooled  = (float*)p; p += (size_t)4*G*H;
  float* gcnt    = (float*)p; p += (size_t)4*G;
  float* partial = (float*)p; p += (size_t)4*nbN*32;

  float* bnscale = par + 4;
  float* bnshift = par + 20;

  // zero-init (ws is re-poisoned 0xAA before every launch)
  hipMemsetAsync(bcnt, 0, (size_t)64*B, stream);
  hipMemsetAsync(bcur, 0, (size_t)64*B, stream);
  hipMemsetAsync(pooled, 0, (size_t)(G*H + G)*sizeof(float), stream);

  k_prep<<<1, 64, 0, stream>>>(We1, ae1, We2, ae2, par);

  // ---- CSR build via locality-first binning ----
  k_bhist<<<nbE, TPB, 0, stream>>>(dstp, bcnt, E);
  k_bscan<<<1, 256, 0, stream>>>(bcnt, bbase, rowptr, B, N, E);
  k_bin<<<nbE, TPB, 0, stream>>>(srcp, dstp, attr, par, bbase, bcur, binned, E);
  k_csr<<<B, 256, 0, stream>>>(binned, bbase, rowptr, csr_src, dotA, dotB, N);

  // ---- layer 1 ----
  k_node1<<<nbN, TPB, 0, stream>>>(x, W1, as1, ad1, A, asn, adn, N);
  k_gat<<<nbG, TPB, 0, stream>>>(rowptr, csr_src, dotA, asn, adn, A, b1, Bv, N);
  k_stats<<<nbN, TPB, 0, stream>>>(Bv, partial, N);
  k_bnprep<<<1, 256, 0, stream>>>(partial, nbN, bn1g, bn1b, bnscale, bnshift, N);

  // ---- layer 2 ----
  k_node2<<<nbN, TPB, 0, stream>>>(Bv, bnscale, bnshift, W2, as2, ad2, A, asn, adn, N);
  k_gat<<<nbG, TPB, 0, stream>>>(rowptr, csr_src, dotB, asn, adn, A, b2, Bv, N);

  // ---- pool + head ----
  k_pool<<<nbN, TPB, 0, stream>>>(Bv, batch, pooled, gcnt, N);
  k_head<<<1, 512, 0, stream>>>(pooled, gcnt, bnl1g, bnl1b, Wl1, bl1, bnl2g, bnl2b, Wl2, bl2,
                                bnl3g, bnl3b, Wl3, bl3, Wo, bo, (float*)d_out, G);
}

// Round 5
// 845.081 us; speedup vs baseline: 1.3266x; 1.3266x over previous
//
#include <hip/hip_runtime.h>
#include <math.h>

#define H 16
#define NF 64
#define TPB 256
#define NB 256        // binning blocks; per-(bucket,block) exclusive ranges
#define SBLK 256
#define SITEMS 12     // scan: 3072/block; M=B*NB=600064 -> 196 blocks <= 256
#define MAXB 2560     // LDS counter capacity (B = ceil(150000/64) = 2344)
#define SRCMASK 0x1FFFFFF

__device__ __forceinline__ float lrelu(float v){ return v > 0.f ? v : 0.2f*v; }

// ---- derived edge-attention weights: par[0..1] = We1@ae1, par[2..3] = We2@ae2 ----
__global__ void k_prep(const float* __restrict__ We1, const float* __restrict__ ae1,
                       const float* __restrict__ We2, const float* __restrict__ ae2,
                       float* __restrict__ params){
  int t = threadIdx.x;
  if (t < 4){
    const float* We = (t < 2) ? We1 : We2;
    const float* ae = (t < 2) ? ae1 : ae2;
    int r = t & 1;
    float s = 0.f;
    for (int c = 0; c < H; ++c) s += We[r*H + c] * ae[c];
    params[t] = s;
  }
}

// ---- pass 1: per-(bucket, block) histogram in LDS; zero global atomics ----
__global__ __launch_bounds__(256) void k_bcount(const int* __restrict__ dst,
    int* __restrict__ cnt, int E, int B, int chunk){
  __shared__ int lcnt[MAXB];
  int blk = blockIdx.x, t = threadIdx.x;
  for (int i = t; i < B; i += 256) lcnt[i] = 0;
  __syncthreads();
  int e0 = blk*chunk, e1 = min(E, e0 + chunk);
  for (int e = e0 + t; e < e1; e += 256) atomicAdd(&lcnt[dst[e] >> 6], 1);
  __syncthreads();
  for (int i = t; i < B; i += 256) cnt[(size_t)i*NB + blk] = lcnt[i];
}

// ---- scan of the count matrix (bucket-major) -> exclusive ranges ----
__global__ __launch_bounds__(SBLK) void k_scan1(const int* __restrict__ cnt,
    int* __restrict__ part, int M){
  __shared__ int red[SBLK];
  int base = blockIdx.x*SBLK*SITEMS;
  int t = threadIdx.x;
  int s = 0;
  for (int i = 0; i < SITEMS; ++i){
    int idx = base + t*SITEMS + i;
    s += (idx < M) ? cnt[idx] : 0;
  }
  red[t] = s; __syncthreads();
  for (int off = SBLK/2; off > 0; off >>= 1){
    if (t < off) red[t] += red[t+off];
    __syncthreads();
  }
  if (t == 0) part[blockIdx.x] = red[0];
}

__global__ __launch_bounds__(SBLK) void k_scan2(int* __restrict__ part, int nb,
    int* __restrict__ bbase, int* __restrict__ rowptr, int B, int N, int E){
  __shared__ int sh[SBLK];
  int t = threadIdx.x;
  int v = (t < nb) ? part[t] : 0;
  sh[t] = v; __syncthreads();
  for (int off = 1; off < SBLK; off <<= 1){
    int add = (t >= off) ? sh[t-off] : 0;
    __syncthreads();
    sh[t] += add;
    __syncthreads();
  }
  if (t < nb) part[t] = sh[t] - v;   // exclusive block offsets
  if (t == 0){ bbase[B] = E; rowptr[N] = E; }
}

__global__ __launch_bounds__(SBLK) void k_scan3(int* __restrict__ cnt,
    const int* __restrict__ part, int* __restrict__ bbase, int M){
  __shared__ int sh[SBLK];
  int base = blockIdx.x*SBLK*SITEMS;
  int t = threadIdx.x;
  int loc[SITEMS]; int s = 0;
  for (int i = 0; i < SITEMS; ++i){
    int idx = base + t*SITEMS + i;
    loc[i] = s;
    s += (idx < M) ? cnt[idx] : 0;
  }
  sh[t] = s; __syncthreads();
  for (int off = 1; off < SBLK; off <<= 1){
    int add = (t >= off) ? sh[t-off] : 0;
    __syncthreads();
    sh[t] += add;
    __syncthreads();
  }
  int toff = sh[t] - s + part[blockIdx.x];
  for (int i = 0; i < SITEMS; ++i){
    int idx = base + t*SITEMS + i;
    if (idx < M){
      int excl = toff + loc[i];
      cnt[idx] = excl;                              // in-place: per-(bucket,block) base
      if ((idx & (NB-1)) == 0) bbase[idx >> 8] = excl;  // bucket base (NB=256)
    }
  }
}

// ---- pass 2: append records into exclusive ranges; LDS cursors, no global atomics ----
__global__ __launch_bounds__(256) void k_bwrite(const int* __restrict__ src,
    const int* __restrict__ dst, const float* __restrict__ attr, const float* __restrict__ wp,
    const int* __restrict__ base, int* __restrict__ key, float2* __restrict__ dot2,
    int E, int B, int chunk){
  __shared__ int lcur[MAXB];
  int blk = blockIdx.x, t = threadIdx.x;
  for (int i = t; i < B; i += 256) lcur[i] = base[(size_t)i*NB + blk];
  __syncthreads();
  float w0 = wp[0], w1 = wp[1], w2 = wp[2], w3 = wp[3];
  int e0 = blk*chunk, e1 = min(E, e0 + chunk);
  for (int e = e0 + t; e < e1; e += 256){
    int d = dst[e];
    int b = d >> 6;
    float2 a = ((const float2*)attr)[e];
    int pos = atomicAdd(&lcur[b], 1);
    key[pos] = src[e] | ((d & 63) << 25);
    dot2[pos] = make_float2(a.x*w0 + a.y*w1, a.x*w2 + a.y*w3);
  }
}

// ---- per-bucket CSR: LDS histogram (key-only read) + wave scan + cursor scatter ----
__global__ __launch_bounds__(256) void k_csr(const int* __restrict__ key,
    const float2* __restrict__ dot2, const int* __restrict__ bbase, int* __restrict__ rowptr,
    int* __restrict__ csr_src, float* __restrict__ dotA, float* __restrict__ dotB, int N){
  __shared__ int lcnt[64];
  __shared__ int lcur[64];
  __shared__ int sr[2];
  int b = blockIdx.x;
  int t = threadIdx.x;
  int node0 = b << 6;
  if (t < 2) sr[t] = bbase[b + t];
  if (t < 64) lcnt[t] = 0;
  __syncthreads();
  int r0 = sr[0], r1 = sr[1];
  for (int i = r0 + t; i < r1; i += 256)
    atomicAdd(&lcnt[((unsigned)key[i]) >> 25], 1);
  __syncthreads();
  if (t < 64){                       // threads 0..63 == wave 0: shfl-scan is safe
    int v = lcnt[t];
    int x = v;
    for (int o = 1; o < 64; o <<= 1){
      int y = __shfl_up(x, o);
      if (t >= o) x += y;
    }
    int excl = x - v;
    lcur[t] = excl;
    if (node0 + t < N) rowptr[node0 + t] = r0 + excl;
  }
  __syncthreads();
  for (int i = r0 + t; i < r1; i += 256){
    int k = key[i];
    int ld = ((unsigned)k) >> 25;
    float2 dd = dot2[i];
    int pos = r0 + atomicAdd(&lcur[ld], 1);
    csr_src[pos] = k & SRCMASK;
    dotA[pos] = dd.x;
    dotB[pos] = dd.y;
  }
}

// ---- layer-1 node transform: h = x @ W1, alpha_src/dst ----
__global__ __launch_bounds__(TPB) void k_node1(const float* __restrict__ x, const float* __restrict__ W,
    const float* __restrict__ av_s, const float* __restrict__ av_d,
    float* __restrict__ hout, float* __restrict__ asn, float* __restrict__ adn, int N){
  __shared__ float sW[NF*H];
  __shared__ float sas[H], sad[H];
  int t = threadIdx.x;
  for (int i = t; i < NF*H; i += TPB) sW[i] = W[i];
  if (t < H){ sas[t] = av_s[t]; sad[t] = av_d[t]; }
  __syncthreads();
  int n = blockIdx.x*TPB + t;
  if (n >= N) return;
  float h[H];
  #pragma unroll
  for (int j = 0; j < H; ++j) h[j] = 0.f;
  const float4* xr = (const float4*)(x + (size_t)n*NF);
  #pragma unroll
  for (int k4 = 0; k4 < NF/4; ++k4){
    float4 xv = xr[k4];
    #pragma unroll
    for (int j = 0; j < H; ++j){
      h[j] += xv.x*sW[(4*k4+0)*H+j] + xv.y*sW[(4*k4+1)*H+j]
            + xv.z*sW[(4*k4+2)*H+j] + xv.w*sW[(4*k4+3)*H+j];
    }
  }
  float4* ho = (float4*)(hout + (size_t)n*H);
  ho[0] = make_float4(h[0],h[1],h[2],h[3]);
  ho[1] = make_float4(h[4],h[5],h[6],h[7]);
  ho[2] = make_float4(h[8],h[9],h[10],h[11]);
  ho[3] = make_float4(h[12],h[13],h[14],h[15]);
  float ss = 0.f, sd = 0.f;
  #pragma unroll
  for (int j = 0; j < H; ++j){ ss += h[j]*sas[j]; sd += h[j]*sad[j]; }
  asn[n] = ss; adn[n] = sd;
}

// ---- fused GAT aggregation: denom + numerator + self-loop + bias + relu, no atomics ----
__global__ __launch_bounds__(TPB) void k_gat(const int* __restrict__ rowptr,
    const int* __restrict__ csr_src, const float* __restrict__ dot,
    const float* __restrict__ asn, const float* __restrict__ adn,
    const float* __restrict__ h, const float* __restrict__ bias,
    float* __restrict__ out, int N){
  int t = threadIdx.x;
  int lane = t & (H-1);
  int n = blockIdx.x*(TPB/H) + (t >> 4);
  if (n >= N) return;
  int r0 = rowptr[n], r1 = rowptr[n+1];
  float adn_n = adn[n];
  float den = 0.f, acc = 0.f, sd = 0.f;
  int i = r0;
  for (; i + 4 <= r1; i += 4){
    int s0 = csr_src[i+0], s1 = csr_src[i+1], s2 = csr_src[i+2], s3 = csr_src[i+3];
    float d0 = dot[i+0], d1 = dot[i+1], d2 = dot[i+2], d3 = dot[i+3];
    float a0 = asn[s0], a1 = asn[s1], a2 = asn[s2], a3 = asn[s3];
    float h0 = h[(size_t)s0*H+lane], h1 = h[(size_t)s1*H+lane],
          h2 = h[(size_t)s2*H+lane], h3 = h[(size_t)s3*H+lane];
    float w0 = __expf(lrelu(a0 + adn_n + d0));
    float w1 = __expf(lrelu(a1 + adn_n + d1));
    float w2 = __expf(lrelu(a2 + adn_n + d2));
    float w3 = __expf(lrelu(a3 + adn_n + d3));
    den += (w0 + w1) + (w2 + w3);
    sd  += (d0 + d1) + (d2 + d3);
    acc += (w0*h0 + w1*h1) + (w2*h2 + w3*h3);
  }
  for (; i < r1; ++i){
    int s = csr_src[i];
    float d = dot[i];
    float w = __expf(lrelu(asn[s] + adn_n + d));
    den += w; sd += d;
    acc += w * h[(size_t)s*H + lane];
  }
  // self-loop: edge_attr = mean of incoming attr -> dot = mean of incoming dots (linear)
  float cntf = (float)(r1 - r0);
  float lael = sd / fmaxf(cntf, 1.f);
  float wl = __expf(lrelu(asn[n] + adn_n + lael));
  den += wl;
  acc += wl * h[(size_t)n*H + lane];
  out[(size_t)n*H + lane] = fmaxf(acc/(den + 1e-16f) + bias[lane], 0.f);
}

// ---- BN sum/sumsq: per-block partials, zero global atomics ----
__global__ __launch_bounds__(TPB) void k_stats(const float* __restrict__ B,
    float* __restrict__ partial, int N){
  __shared__ float lds[4][32];
  int t = threadIdx.x;
  int n = blockIdx.x*TPB + t;
  float v[H];
  if (n < N){
    const float4* br = (const float4*)(B + (size_t)n*H);
    float4 a0 = br[0], a1 = br[1], a2 = br[2], a3 = br[3];
    v[0]=a0.x; v[1]=a0.y; v[2]=a0.z; v[3]=a0.w;
    v[4]=a1.x; v[5]=a1.y; v[6]=a1.z; v[7]=a1.w;
    v[8]=a2.x; v[9]=a2.y; v[10]=a2.z; v[11]=a2.w;
    v[12]=a3.x; v[13]=a3.y; v[14]=a3.z; v[15]=a3.w;
  } else {
    #pragma unroll
    for (int f = 0; f < H; ++f) v[f] = 0.f;
  }
  float s[H], q[H];
  #pragma unroll
  for (int f = 0; f < H; ++f){ s[f] = v[f]; q[f] = v[f]*v[f]; }
  for (int m = 1; m < 64; m <<= 1){
    #pragma unroll
    for (int f = 0; f < H; ++f){
      s[f] += __shfl_xor(s[f], m);
      q[f] += __shfl_xor(q[f], m);
    }
  }
  int wave = t >> 6, lane = t & 63;
  if (lane == 0){
    #pragma unroll
    for (int f = 0; f < H; ++f){ lds[wave][f] = s[f]; lds[wave][H+f] = q[f]; }
  }
  __syncthreads();
  if (t < 32)
    partial[(size_t)blockIdx.x*32 + t] = lds[0][t] + lds[1][t] + lds[2][t] + lds[3][t];
}

// ---- final BN reduction over block partials + scale/shift ----
__global__ __launch_bounds__(256) void k_bnprep(const float* __restrict__ partial, int nb,
    const float* __restrict__ gamma, const float* __restrict__ beta,
    float* __restrict__ scale, float* __restrict__ shift, int N){
  __shared__ float red[256];
  __shared__ float tot[32];
  int t = threadIdx.x;
  int f = t & 31, c = t >> 5;        // 8 chunks x 32 features
  float s = 0.f;
  for (int b = c; b < nb; b += 8) s += partial[(size_t)b*32 + f];
  red[c*32 + f] = s;
  __syncthreads();
  if (t < 32){
    float S = 0.f;
    #pragma unroll
    for (int cc = 0; cc < 8; ++cc) S += red[cc*32 + t];
    tot[t] = S;
  }
  __syncthreads();
  if (t < H){
    float inv = 1.f / (float)N;
    float mu  = tot[t] * inv;
    float var = tot[H+t] * inv - mu*mu;
    float sc  = gamma[t] * rsqrtf(var + 1e-5f);
    scale[t] = sc;
    shift[t] = beta[t] - mu*sc;
  }
}

// ---- layer-2 node transform: BN + h = xn @ W2 + alphas ----
__global__ __launch_bounds__(TPB) void k_node2(const float* __restrict__ Bin, const float* __restrict__ scale,
    const float* __restrict__ shift, const float* __restrict__ W,
    const float* __restrict__ av_s, const float* __restrict__ av_d,
    float* __restrict__ hout, float* __restrict__ asn, float* __restrict__ adn, int N){
  __shared__ float sW[H*H];
  __shared__ float ssc[H], ssh[H], sas[H], sad[H];
  int t = threadIdx.x;
  if (t < H*H) sW[t] = W[t];
  if (t < H){ ssc[t] = scale[t]; ssh[t] = shift[t]; sas[t] = av_s[t]; sad[t] = av_d[t]; }
  __syncthreads();
  int n = blockIdx.x*TPB + t;
  if (n >= N) return;
  const float4* br = (const float4*)(Bin + (size_t)n*H);
  float4 a0 = br[0], a1 = br[1], a2 = br[2], a3 = br[3];
  float xn[H] = {a0.x,a0.y,a0.z,a0.w, a1.x,a1.y,a1.z,a1.w,
                 a2.x,a2.y,a2.z,a2.w, a3.x,a3.y,a3.z,a3.w};
  #pragma unroll
  for (int f = 0; f < H; ++f) xn[f] = xn[f]*ssc[f] + ssh[f];
  float h[H];
  #pragma unroll
  for (int j = 0; j < H; ++j) h[j] = 0.f;
  #pragma unroll
  for (int k = 0; k < H; ++k){
    float xv = xn[k];
    #pragma unroll
    for (int j = 0; j < H; ++j) h[j] += xv * sW[k*H+j];
  }
  float4* ho = (float4*)(hout + (size_t)n*H);
  ho[0] = make_float4(h[0],h[1],h[2],h[3]);
  ho[1] = make_float4(h[4],h[5],h[6],h[7]);
  ho[2] = make_float4(h[8],h[9],h[10],h[11]);
  ho[3] = make_float4(h[12],h[13],h[14],h[15]);
  float ss = 0.f, sd = 0.f;
  #pragma unroll
  for (int j = 0; j < H; ++j){ ss += h[j]*sas[j]; sd += h[j]*sad[j]; }
  asn[n] = ss; adn[n] = sd;
}

// ---- mean-pool accumulation; batch is sorted -> wave-uniform fast path ----
__global__ __launch_bounds__(TPB) void k_pool(const float* __restrict__ B,
    const int* __restrict__ batch, float* __restrict__ pooled, float* __restrict__ gcnt, int N){
  int n = blockIdx.x*TPB + threadIdx.x;
  int lane = threadIdx.x & 63;
  bool valid = n < N;
  int g = valid ? batch[n] : -1;
  float v[H];
  if (valid){
    const float4* br = (const float4*)(B + (size_t)n*H);
    float4 a0 = br[0], a1 = br[1], a2 = br[2], a3 = br[3];
    v[0]=a0.x; v[1]=a0.y; v[2]=a0.z; v[3]=a0.w;
    v[4]=a1.x; v[5]=a1.y; v[6]=a1.z; v[7]=a1.w;
    v[8]=a2.x; v[9]=a2.y; v[10]=a2.z; v[11]=a2.w;
    v[12]=a3.x; v[13]=a3.y; v[14]=a3.z; v[15]=a3.w;
  } else {
    #pragma unroll
    for (int f = 0; f < H; ++f) v[f] = 0.f;
  }
  int g0 = __shfl(g, 0);
  bool allsame = __all(valid && g == g0);
  if (allsame){
    float s[H];
    #pragma unroll
    for (int f = 0; f < H; ++f) s[f] = v[f];
    for (int m = 1; m < 64; m <<= 1){
      #pragma unroll
      for (int f = 0; f < H; ++f) s[f] += __shfl_xor(s[f], m);
    }
    if (lane == 0){
      float* p = pooled + (size_t)g0*H;
      #pragma unroll
      for (int f = 0; f < H; ++f) atomicAdd(&p[f], s[f]);
      atomicAdd(&gcnt[g0], 64.f);
    }
  } else if (valid){
    float* p = pooled + (size_t)g*H;
    #pragma unroll
    for (int f = 0; f < H; ++f) atomicAdd(&p[f], v[f]);
    atomicAdd(&gcnt[g], 1.f);
  }
}

// ---- D2RL head: one block of 512 threads (one per graph) ----
__device__ void block_stats16(const float* v, float* mu, float* rs,
                              float* wsum, float* wsq, int G){
  float s[H], q[H];
  #pragma unroll
  for (int f = 0; f < H; ++f){ s[f] = v[f]; q[f] = v[f]*v[f]; }
  for (int m = 1; m < 64; m <<= 1){
    #pragma unroll
    for (int f = 0; f < H; ++f){
      s[f] += __shfl_xor(s[f], m);
      q[f] += __shfl_xor(q[f], m);
    }
  }
  int wave = threadIdx.x >> 6, lane = threadIdx.x & 63;
  if (lane == 0){
    #pragma unroll
    for (int f = 0; f < H; ++f){ wsum[wave*H+f] = s[f]; wsq[wave*H+f] = q[f]; }
  }
  __syncthreads();
  int t = threadIdx.x;
  if (t < H){
    float S = 0.f, Q = 0.f;
    for (int w = 0; w < 8; ++w){ S += wsum[w*H+t]; Q += wsq[w*H+t]; }
    float m_ = S / (float)G;
    float var = Q / (float)G - m_*m_;
    mu[t] = m_;
    rs[t] = rsqrtf(var + 1e-5f);
  }
  __syncthreads();
}

__global__ __launch_bounds__(512) void k_head(const float* __restrict__ pooled, const float* __restrict__ gcnt,
    const float* __restrict__ g1, const float* __restrict__ be1,
    const float* __restrict__ Wl1, const float* __restrict__ bl1,
    const float* __restrict__ g2, const float* __restrict__ be2,
    const float* __restrict__ Wl2, const float* __restrict__ bl2,
    const float* __restrict__ g3, const float* __restrict__ be3,
    const float* __restrict__ Wl3, const float* __restrict__ bl3,
    const float* __restrict__ Wo, const float* __restrict__ bo,
    float* __restrict__ out, int G){
  __shared__ float wsum[8*H], wsq[8*H];
  __shared__ float pmu[H], prs[H], smu[H], srs[H];
  int g = threadIdx.x;
  float p[H];
  if (g < G){
    float c = fmaxf(gcnt[g], 1.f);
    #pragma unroll
    for (int f = 0; f < H; ++f) p[f] = pooled[(size_t)g*H+f] / c;
  } else {
    #pragma unroll
    for (int f = 0; f < H; ++f) p[f] = 0.f;
  }
  block_stats16(p, pmu, prs, wsum, wsq, G);
  float xn[H], z[H];
  #pragma unroll
  for (int f = 0; f < H; ++f) xn[f] = g1[f]*(p[f]-pmu[f])*prs[f] + be1[f];
  #pragma unroll
  for (int j = 0; j < H; ++j) z[j] = bl1[j];
  for (int k = 0; k < H; ++k){
    float xv = xn[k];
    #pragma unroll
    for (int j = 0; j < H; ++j) z[j] += xv * Wl1[k*H+j];
  }
  #pragma unroll
  for (int j = 0; j < H; ++j) z[j] = fmaxf(z[j], 0.f);
  block_stats16(z, smu, srs, wsum, wsq, G);
  float x2[2*H], z2[H];
  #pragma unroll
  for (int f = 0; f < H; ++f){
    x2[f]   = g2[f]  *(z[f]-smu[f])*srs[f] + be2[f];
    x2[H+f] = g2[H+f]*(p[f]-pmu[f])*prs[f] + be2[H+f];
  }
  #pragma unroll
  for (int j = 0; j < H; ++j) z2[j] = bl2[j];
  for (int k = 0; k < 2*H; ++k){
    float xv = x2[k];
    #pragma unroll
    for (int j = 0; j < H; ++j) z2[j] += xv * Wl2[k*H+j];
  }
  #pragma unroll
  for (int j = 0; j < H; ++j) z2[j] = fmaxf(z2[j], 0.f);
  block_stats16(z2, smu, srs, wsum, wsq, G);
  float x3[2*H], z3[H];
  #pragma unroll
  for (int f = 0; f < H; ++f){
    x3[f]   = g3[f]  *(z2[f]-smu[f])*srs[f] + be3[f];
    x3[H+f] = g3[H+f]*(p[f]-pmu[f])*prs[f] + be3[H+f];
  }
  #pragma unroll
  for (int j = 0; j < H; ++j) z3[j] = bl3[j];
  for (int k = 0; k < 2*H; ++k){
    float xv = x3[k];
    #pragma unroll
    for (int j = 0; j < H; ++j) z3[j] += xv * Wl3[k*H+j];
  }
  #pragma unroll
  for (int j = 0; j < H; ++j) z3[j] = fmaxf(z3[j], 0.f);
  if (g < G){
    float o = bo[0];
    #pragma unroll
    for (int j = 0; j < H; ++j) o += z3[j]*Wo[j];
    out[g] = o;
  }
}

extern "C" void kernel_launch(void* const* d_in, const int* in_sizes, int n_in,
                              void* d_out, int out_size, void* d_ws, size_t ws_size,
                              hipStream_t stream) {
  const float* x     = (const float*)d_in[0];
  const int*   ei    = (const int*)d_in[1];
  const float* attr  = (const float*)d_in[2];
  const int*   batch = (const int*)d_in[3];
  const float* W1  = (const float*)d_in[4];
  const float* We1 = (const float*)d_in[5];
  const float* as1 = (const float*)d_in[6];
  const float* ad1 = (const float*)d_in[7];
  const float* ae1 = (const float*)d_in[8];
  const float* b1  = (const float*)d_in[9];
  const float* bn1g = (const float*)d_in[10];
  const float* bn1b = (const float*)d_in[11];
  const float* W2  = (const float*)d_in[12];
  const float* We2 = (const float*)d_in[13];
  const float* as2 = (const float*)d_in[14];
  const float* ad2 = (const float*)d_in[15];
  const float* ae2 = (const float*)d_in[16];
  const float* b2  = (const float*)d_in[17];
  const float* bnl1g = (const float*)d_in[18];
  const float* bnl1b = (const float*)d_in[19];
  const float* Wl1 = (const float*)d_in[20];
  const float* bl1 = (const float*)d_in[21];
  const float* bnl2g = (const float*)d_in[22];
  const float* bnl2b = (const float*)d_in[23];
  const float* Wl2 = (const float*)d_in[24];
  const float* bl2 = (const float*)d_in[25];
  const float* bnl3g = (const float*)d_in[26];
  const float* bnl3b = (const float*)d_in[27];
  const float* Wl3 = (const float*)d_in[28];
  const float* bl3 = (const float*)d_in[29];
  const float* Wo  = (const float*)d_in[30];
  const float* bo  = (const float*)d_in[31];

  int N = in_sizes[0] / NF;
  int E = in_sizes[1] / 2;
  int G = out_size;
  const int* srcp = ei;
  const int* dstp = ei + E;

  int B     = (N + 63) >> 6;                         // buckets of 64 dst nodes (2344)
  int M     = B * NB;                                // count-matrix size (600064)
  int chunk = (E + NB - 1) / NB;                     // edges per binning block
  int nbN   = (N + TPB - 1)/TPB;
  int nbS   = (M + SBLK*SITEMS - 1)/(SBLK*SITEMS);   // scan blocks (196 <= 256)
  int nbG   = (N + (TPB/H) - 1)/(TPB/H);             // k_gat blocks (16 nodes/block)

  // ---- workspace layout ----
  // binned region (key 4B*E + dot2 8B*E = 57.6MB) is dead after k_csr;
  // A/Bv/asn/adn (20.4MB) alias on top of it.
  char* wsb = (char*)d_ws;
  int*    key  = (int*)wsb;                          // [0, 4E)
  float2* dot2 = (float2*)(wsb + (size_t)4*E);       // [4E, 12E)
  float* A   = (float*)wsb;                          // 16N floats (alias, post-CSR)
  float* Bv  = A  + (size_t)16*N;
  float* asn = Bv + (size_t)16*N;
  float* adn = asn + N;
  char* p = wsb + (size_t)12*E;
  int*   csr_src = (int*)p;   p += (size_t)4*E;
  float* dotA    = (float*)p; p += (size_t)4*E;
  float* dotB    = (float*)p; p += (size_t)4*E;
  int*   rowptr  = (int*)p;   p += (size_t)4*(N+1);
  int*   bbase   = (int*)p;   p += (size_t)4*(B+1);
  int*   cnt     = (int*)p;   p += (size_t)4*M;      // per-(bucket,block) counts -> bases
  int*   part    = (int*)p;   p += (size_t)4*256;
  float* par     = (float*)p; p += 4*64;             // [0..3]=wp [4..19]=scale [20..35]=shift
  float* pooled  = (float*)p; p += (size_t)4*G*H;
  float* gcnt    = (float*)p; p += (size_t)4*G;
  float* partial = (float*)p; p += (size_t)4*nbN*32;

  float* bnscale = par + 4;
  float* bnshift = par + 20;

  // zero-init (ws is re-poisoned 0xAA before every launch)
  hipMemsetAsync(pooled, 0, (size_t)(G*H + G)*sizeof(float), stream);

  k_prep<<<1, 64, 0, stream>>>(We1, ae1, We2, ae2, par);

  // ---- CSR build: two-pass exclusive-range binning (no global atomics) ----
  k_bcount<<<NB, 256, 0, stream>>>(dstp, cnt, E, B, chunk);
  k_scan1<<<nbS, SBLK, 0, stream>>>(cnt, part, M);
  k_scan2<<<1, SBLK, 0, stream>>>(part, nbS, bbase, rowptr, B, N, E);
  k_scan3<<<nbS, SBLK, 0, stream>>>(cnt, part, bbase, M);
  k_bwrite<<<NB, 256, 0, stream>>>(srcp, dstp, attr, par, cnt, key, dot2, E, B, chunk);
  k_csr<<<B, 256, 0, stream>>>(key, dot2, bbase, rowptr, csr_src, dotA, dotB, N);

  // ---- layer 1 ----
  k_node1<<<nbN, TPB, 0, stream>>>(x, W1, as1, ad1, A, asn, adn, N);
  k_gat<<<nbG, TPB, 0, stream>>>(rowptr, csr_src, dotA, asn, adn, A, b1, Bv, N);
  k_stats<<<nbN, TPB, 0, stream>>>(Bv, partial, N);
  k_bnprep<<<1, 256, 0, stream>>>(partial, nbN, bn1g, bn1b, bnscale, bnshift, N);

  // ---- layer 2 ----
  k_node2<<<nbN, TPB, 0, stream>>>(Bv, bnscale, bnshift, W2, as2, ad2, A, asn, adn, N);
  k_gat<<<nbG, TPB, 0, stream>>>(rowptr, csr_src, dotB, asn, adn, A, b2, Bv, N);

  // ---- pool + head ----
  k_pool<<<nbN, TPB, 0, stream>>>(Bv, batch, pooled, gcnt, N);
  k_head<<<1, 512, 0, stream>>>(pooled, gcnt, bnl1g, bnl1b, Wl1, bl1, bnl2g, bnl2b, Wl2, bl2,
                                bnl3g, bnl3b, Wl3, bl3, Wo, bo, (float*)d_out, G);
}

// Round 6
// 792.543 us; speedup vs baseline: 1.4145x; 1.0663x over previous
//
#include <hip/hip_runtime.h>
#include <math.h>

#define H 16
#define NF 64
#define TPB 256
#define NB 256        // binning blocks
#define BTPB 1024     // binning threads per block (16 waves -> latency hiding)
#define NSHIFT 10     // coarse bucket = 1024 consecutive dst nodes
#define MAXB2 192     // LDS counter capacity (B = ceil(150000/1024) = 147)
#define SBLK 256
#define SITEMS 2      // scan: 512/block; M=147*256=37632 -> 74 blocks <= 256
#define SRCMASK 0x3FFFF

__device__ __forceinline__ float lrelu(float v){ return v > 0.f ? v : 0.2f*v; }

// ---- derived edge-attention weights: par[0..1] = We1@ae1, par[2..3] = We2@ae2 ----
__global__ void k_prep(const float* __restrict__ We1, const float* __restrict__ ae1,
                       const float* __restrict__ We2, const float* __restrict__ ae2,
                       float* __restrict__ params){
  int t = threadIdx.x;
  if (t < 4){
    const float* We = (t < 2) ? We1 : We2;
    const float* ae = (t < 2) ? ae1 : ae2;
    int r = t & 1;
    float s = 0.f;
    for (int c = 0; c < H; ++c) s += We[r*H + c] * ae[c];
    params[t] = s;
  }
}

// ---- pass 1: per-(coarse bucket, block) histogram in LDS ----
__global__ __launch_bounds__(BTPB) void k_bcount(const int* __restrict__ dst,
    int* __restrict__ cnt, int E, int B, int chunk){
  __shared__ int lcnt[MAXB2];
  int blk = blockIdx.x, t = threadIdx.x;
  for (int i = t; i < B; i += BTPB) lcnt[i] = 0;
  __syncthreads();
  int e0 = blk*chunk, e1 = min(E, e0 + chunk);
  for (int e = e0 + t; e < e1; e += BTPB) atomicAdd(&lcnt[dst[e] >> NSHIFT], 1);
  __syncthreads();
  for (int i = t; i < B; i += BTPB) cnt[(size_t)i*NB + blk] = lcnt[i];
}

// ---- scan of the count matrix (bucket-major) -> exclusive ranges ----
__global__ __launch_bounds__(SBLK) void k_scan1(const int* __restrict__ cnt,
    int* __restrict__ part, int M){
  __shared__ int red[SBLK];
  int base = blockIdx.x*SBLK*SITEMS;
  int t = threadIdx.x;
  int s = 0;
  for (int i = 0; i < SITEMS; ++i){
    int idx = base + t*SITEMS + i;
    s += (idx < M) ? cnt[idx] : 0;
  }
  red[t] = s; __syncthreads();
  for (int off = SBLK/2; off > 0; off >>= 1){
    if (t < off) red[t] += red[t+off];
    __syncthreads();
  }
  if (t == 0) part[blockIdx.x] = red[0];
}

__global__ __launch_bounds__(SBLK) void k_scan2(int* __restrict__ part, int nb,
    int* __restrict__ bbase, int* __restrict__ rowptr, int B, int N, int E){
  __shared__ int sh[SBLK];
  int t = threadIdx.x;
  int v = (t < nb) ? part[t] : 0;
  sh[t] = v; __syncthreads();
  for (int off = 1; off < SBLK; off <<= 1){
    int add = (t >= off) ? sh[t-off] : 0;
    __syncthreads();
    sh[t] += add;
    __syncthreads();
  }
  if (t < nb) part[t] = sh[t] - v;   // exclusive block offsets
  if (t == 0){ bbase[B] = E; rowptr[N] = E; }
}

__global__ __launch_bounds__(SBLK) void k_scan3(int* __restrict__ cnt,
    const int* __restrict__ part, int* __restrict__ bbase, int M){
  __shared__ int sh[SBLK];
  int base = blockIdx.x*SBLK*SITEMS;
  int t = threadIdx.x;
  int loc[SITEMS]; int s = 0;
  for (int i = 0; i < SITEMS; ++i){
    int idx = base + t*SITEMS + i;
    loc[i] = s;
    s += (idx < M) ? cnt[idx] : 0;
  }
  sh[t] = s; __syncthreads();
  for (int off = 1; off < SBLK; off <<= 1){
    int add = (t >= off) ? sh[t-off] : 0;
    __syncthreads();
    sh[t] += add;
    __syncthreads();
  }
  int toff = sh[t] - s + part[blockIdx.x];
  for (int i = 0; i < SITEMS; ++i){
    int idx = base + t*SITEMS + i;
    if (idx < M){
      int excl = toff + loc[i];
      cnt[idx] = excl;                              // in-place: per-(bucket,block) base
      if ((idx & (NB-1)) == 0) bbase[idx >> 8] = excl;  // bucket base (NB=256)
    }
  }
}

// ---- pass 2: append records into exclusive ranges (avg 127 edges -> ~1x write amp;
//      frontier 32 blk/XCD x 147 buckets ~ 300KB, L2-resident) ----
__global__ __launch_bounds__(BTPB) void k_bwrite(const int* __restrict__ src,
    const int* __restrict__ dst, const float* __restrict__ attr, const float* __restrict__ wp,
    const int* __restrict__ base, int* __restrict__ key, float2* __restrict__ dot2,
    int E, int B, int chunk){
  __shared__ int lcur[MAXB2];
  int blk = blockIdx.x, t = threadIdx.x;
  for (int i = t; i < B; i += BTPB) lcur[i] = base[(size_t)i*NB + blk];
  __syncthreads();
  float w0 = wp[0], w1 = wp[1], w2 = wp[2], w3 = wp[3];
  int e0 = blk*chunk, e1 = min(E, e0 + chunk);
  for (int e = e0 + t; e < e1; e += BTPB){
    int d = dst[e];
    int b = d >> NSHIFT;
    float2 a = ((const float2*)attr)[e];
    int pos = atomicAdd(&lcur[b], 1);
    key[pos] = src[e] | ((d & 1023) << 18);
    dot2[pos] = make_float2(a.x*w0 + a.y*w1, a.x*w2 + a.y*w3);
  }
}

// ---- per-bucket CSR: 1024 LDS counters, block scan, cursor scatter ----
__global__ __launch_bounds__(1024) void k_csr(const int* __restrict__ key,
    const float2* __restrict__ dot2, const int* __restrict__ bbase, int* __restrict__ rowptr,
    int* __restrict__ csr_src, float* __restrict__ dotA, float* __restrict__ dotB, int N){
  __shared__ int lcnt[1024];
  __shared__ int lcur[1024];
  __shared__ int wsum[16];
  __shared__ int sr[2];
  int b = blockIdx.x;
  int t = threadIdx.x;
  int node0 = b << NSHIFT;
  if (t < 2) sr[t] = bbase[b + t];
  lcnt[t] = 0;
  __syncthreads();
  int r0 = sr[0], r1 = sr[1];
  for (int i = r0 + t; i < r1; i += 1024)
    atomicAdd(&lcnt[((unsigned)key[i]) >> 18], 1);
  __syncthreads();
  int v = lcnt[t];
  int lane = t & 63, wave = t >> 6;
  int x = v;
  for (int o = 1; o < 64; o <<= 1){
    int y = __shfl_up(x, o);
    if (lane >= o) x += y;
  }
  if (lane == 63) wsum[wave] = x;
  __syncthreads();
  if (t == 0){
    int s = 0;
    #pragma unroll
    for (int w = 0; w < 16; ++w){ int tmp = wsum[w]; wsum[w] = s; s += tmp; }
  }
  __syncthreads();
  int excl = x - v + wsum[wave];
  lcur[t] = excl;
  if (node0 + t < N) rowptr[node0 + t] = r0 + excl;
  __syncthreads();
  for (int i = r0 + t; i < r1; i += 1024){
    int k = key[i];
    int ld = ((unsigned)k) >> 18;
    float2 dd = dot2[i];
    int pos = r0 + atomicAdd(&lcur[ld], 1);
    csr_src[pos] = k & SRCMASK;
    dotA[pos] = dd.x;
    dotB[pos] = dd.y;
  }
}

// ---- layer-1 node transform: h = x @ W1, alpha_src/dst ----
__global__ __launch_bounds__(TPB) void k_node1(const float* __restrict__ x, const float* __restrict__ W,
    const float* __restrict__ av_s, const float* __restrict__ av_d,
    float* __restrict__ hout, float* __restrict__ asn, float* __restrict__ adn, int N){
  __shared__ float sW[NF*H];
  __shared__ float sas[H], sad[H];
  int t = threadIdx.x;
  for (int i = t; i < NF*H; i += TPB) sW[i] = W[i];
  if (t < H){ sas[t] = av_s[t]; sad[t] = av_d[t]; }
  __syncthreads();
  int n = blockIdx.x*TPB + t;
  if (n >= N) return;
  float h[H];
  #pragma unroll
  for (int j = 0; j < H; ++j) h[j] = 0.f;
  const float4* xr = (const float4*)(x + (size_t)n*NF);
  #pragma unroll
  for (int k4 = 0; k4 < NF/4; ++k4){
    float4 xv = xr[k4];
    #pragma unroll
    for (int j = 0; j < H; ++j){
      h[j] += xv.x*sW[(4*k4+0)*H+j] + xv.y*sW[(4*k4+1)*H+j]
            + xv.z*sW[(4*k4+2)*H+j] + xv.w*sW[(4*k4+3)*H+j];
    }
  }
  float4* ho = (float4*)(hout + (size_t)n*H);
  ho[0] = make_float4(h[0],h[1],h[2],h[3]);
  ho[1] = make_float4(h[4],h[5],h[6],h[7]);
  ho[2] = make_float4(h[8],h[9],h[10],h[11]);
  ho[3] = make_float4(h[12],h[13],h[14],h[15]);
  float ss = 0.f, sd = 0.f;
  #pragma unroll
  for (int j = 0; j < H; ++j){ ss += h[j]*sas[j]; sd += h[j]*sad[j]; }
  asn[n] = ss; adn[n] = sd;
}

// ---- fused GAT aggregation: denom + numerator + self-loop + bias + relu, no atomics ----
__global__ __launch_bounds__(TPB) void k_gat(const int* __restrict__ rowptr,
    const int* __restrict__ csr_src, const float* __restrict__ dot,
    const float* __restrict__ asn, const float* __restrict__ adn,
    const float* __restrict__ h, const float* __restrict__ bias,
    float* __restrict__ out, int N){
  int t = threadIdx.x;
  int lane = t & (H-1);
  int n = blockIdx.x*(TPB/H) + (t >> 4);
  if (n >= N) return;
  int r0 = rowptr[n], r1 = rowptr[n+1];
  float adn_n = adn[n];
  float den = 0.f, acc = 0.f, sd = 0.f;
  int i = r0;
  for (; i + 4 <= r1; i += 4){
    int s0 = csr_src[i+0], s1 = csr_src[i+1], s2 = csr_src[i+2], s3 = csr_src[i+3];
    float d0 = dot[i+0], d1 = dot[i+1], d2 = dot[i+2], d3 = dot[i+3];
    float a0 = asn[s0], a1 = asn[s1], a2 = asn[s2], a3 = asn[s3];
    float h0 = h[(size_t)s0*H+lane], h1 = h[(size_t)s1*H+lane],
          h2 = h[(size_t)s2*H+lane], h3 = h[(size_t)s3*H+lane];
    float w0 = __expf(lrelu(a0 + adn_n + d0));
    float w1 = __expf(lrelu(a1 + adn_n + d1));
    float w2 = __expf(lrelu(a2 + adn_n + d2));
    float w3 = __expf(lrelu(a3 + adn_n + d3));
    den += (w0 + w1) + (w2 + w3);
    sd  += (d0 + d1) + (d2 + d3);
    acc += (w0*h0 + w1*h1) + (w2*h2 + w3*h3);
  }
  for (; i < r1; ++i){
    int s = csr_src[i];
    float d = dot[i];
    float w = __expf(lrelu(asn[s] + adn_n + d));
    den += w; sd += d;
    acc += w * h[(size_t)s*H + lane];
  }
  // self-loop: edge_attr = mean of incoming attr -> dot = mean of incoming dots (linear)
  float cntf = (float)(r1 - r0);
  float lael = sd / fmaxf(cntf, 1.f);
  float wl = __expf(lrelu(asn[n] + adn_n + lael));
  den += wl;
  acc += wl * h[(size_t)n*H + lane];
  out[(size_t)n*H + lane] = fmaxf(acc/(den + 1e-16f) + bias[lane], 0.f);
}

// ---- BN sum/sumsq: per-block partials, zero global atomics ----
__global__ __launch_bounds__(TPB) void k_stats(const float* __restrict__ B,
    float* __restrict__ partial, int N){
  __shared__ float lds[4][32];
  int t = threadIdx.x;
  int n = blockIdx.x*TPB + t;
  float v[H];
  if (n < N){
    const float4* br = (const float4*)(B + (size_t)n*H);
    float4 a0 = br[0], a1 = br[1], a2 = br[2], a3 = br[3];
    v[0]=a0.x; v[1]=a0.y; v[2]=a0.z; v[3]=a0.w;
    v[4]=a1.x; v[5]=a1.y; v[6]=a1.z; v[7]=a1.w;
    v[8]=a2.x; v[9]=a2.y; v[10]=a2.z; v[11]=a2.w;
    v[12]=a3.x; v[13]=a3.y; v[14]=a3.z; v[15]=a3.w;
  } else {
    #pragma unroll
    for (int f = 0; f < H; ++f) v[f] = 0.f;
  }
  float s[H], q[H];
  #pragma unroll
  for (int f = 0; f < H; ++f){ s[f] = v[f]; q[f] = v[f]*v[f]; }
  for (int m = 1; m < 64; m <<= 1){
    #pragma unroll
    for (int f = 0; f < H; ++f){
      s[f] += __shfl_xor(s[f], m);
      q[f] += __shfl_xor(q[f], m);
    }
  }
  int wave = t >> 6, lane = t & 63;
  if (lane == 0){
    #pragma unroll
    for (int f = 0; f < H; ++f){ lds[wave][f] = s[f]; lds[wave][H+f] = q[f]; }
  }
  __syncthreads();
  if (t < 32)
    partial[(size_t)blockIdx.x*32 + t] = lds[0][t] + lds[1][t] + lds[2][t] + lds[3][t];
}

// ---- final BN reduction over block partials + scale/shift ----
__global__ __launch_bounds__(256) void k_bnprep(const float* __restrict__ partial, int nb,
    const float* __restrict__ gamma, const float* __restrict__ beta,
    float* __restrict__ scale, float* __restrict__ shift, int N){
  __shared__ float red[256];
  __shared__ float tot[32];
  int t = threadIdx.x;
  int f = t & 31, c = t >> 5;        // 8 chunks x 32 features
  float s = 0.f;
  for (int b = c; b < nb; b += 8) s += partial[(size_t)b*32 + f];
  red[c*32 + f] = s;
  __syncthreads();
  if (t < 32){
    float S = 0.f;
    #pragma unroll
    for (int cc = 0; cc < 8; ++cc) S += red[cc*32 + t];
    tot[t] = S;
  }
  __syncthreads();
  if (t < H){
    float inv = 1.f / (float)N;
    float mu  = tot[t] * inv;
    float var = tot[H+t] * inv - mu*mu;
    float sc  = gamma[t] * rsqrtf(var + 1e-5f);
    scale[t] = sc;
    shift[t] = beta[t] - mu*sc;
  }
}

// ---- layer-2 node transform: BN + h = xn @ W2 + alphas ----
__global__ __launch_bounds__(TPB) void k_node2(const float* __restrict__ Bin, const float* __restrict__ scale,
    const float* __restrict__ shift, const float* __restrict__ W,
    const float* __restrict__ av_s, const float* __restrict__ av_d,
    float* __restrict__ hout, float* __restrict__ asn, float* __restrict__ adn, int N){
  __shared__ float sW[H*H];
  __shared__ float ssc[H], ssh[H], sas[H], sad[H];
  int t = threadIdx.x;
  if (t < H*H) sW[t] = W[t];
  if (t < H){ ssc[t] = scale[t]; ssh[t] = shift[t]; sas[t] = av_s[t]; sad[t] = av_d[t]; }
  __syncthreads();
  int n = blockIdx.x*TPB + t;
  if (n >= N) return;
  const float4* br = (const float4*)(Bin + (size_t)n*H);
  float4 a0 = br[0], a1 = br[1], a2 = br[2], a3 = br[3];
  float xn[H] = {a0.x,a0.y,a0.z,a0.w, a1.x,a1.y,a1.z,a1.w,
                 a2.x,a2.y,a2.z,a2.w, a3.x,a3.y,a3.z,a3.w};
  #pragma unroll
  for (int f = 0; f < H; ++f) xn[f] = xn[f]*ssc[f] + ssh[f];
  float h[H];
  #pragma unroll
  for (int j = 0; j < H; ++j) h[j] = 0.f;
  #pragma unroll
  for (int k = 0; k < H; ++k){
    float xv = xn[k];
    #pragma unroll
    for (int j = 0; j < H; ++j) h[j] += xv * sW[k*H+j];
  }
  float4* ho = (float4*)(hout + (size_t)n*H);
  ho[0] = make_float4(h[0],h[1],h[2],h[3]);
  ho[1] = make_float4(h[4],h[5],h[6],h[7]);
  ho[2] = make_float4(h[8],h[9],h[10],h[11]);
  ho[3] = make_float4(h[12],h[13],h[14],h[15]);
  float ss = 0.f, sd = 0.f;
  #pragma unroll
  for (int j = 0; j < H; ++j){ ss += h[j]*sas[j]; sd += h[j]*sad[j]; }
  asn[n] = ss; adn[n] = sd;
}

// ---- mean-pool accumulation; batch is sorted -> wave-uniform fast path ----
__global__ __launch_bounds__(TPB) void k_pool(const float* __restrict__ B,
    const int* __restrict__ batch, float* __restrict__ pooled, float* __restrict__ gcnt, int N){
  int n = blockIdx.x*TPB + threadIdx.x;
  int lane = threadIdx.x & 63;
  bool valid = n < N;
  int g = valid ? batch[n] : -1;
  float v[H];
  if (valid){
    const float4* br = (const float4*)(B + (size_t)n*H);
    float4 a0 = br[0], a1 = br[1], a2 = br[2], a3 = br[3];
    v[0]=a0.x; v[1]=a0.y; v[2]=a0.z; v[3]=a0.w;
    v[4]=a1.x; v[5]=a1.y; v[6]=a1.z; v[7]=a1.w;
    v[8]=a2.x; v[9]=a2.y; v[10]=a2.z; v[11]=a2.w;
    v[12]=a3.x; v[13]=a3.y; v[14]=a3.z; v[15]=a3.w;
  } else {
    #pragma unroll
    for (int f = 0; f < H; ++f) v[f] = 0.f;
  }
  int g0 = __shfl(g, 0);
  bool allsame = __all(valid && g == g0);
  if (allsame){
    float s[H];
    #pragma unroll
    for (int f = 0; f < H; ++f) s[f] = v[f];
    for (int m = 1; m < 64; m <<= 1){
      #pragma unroll
      for (int f = 0; f < H; ++f) s[f] += __shfl_xor(s[f], m);
    }
    if (lane == 0){
      float* p = pooled + (size_t)g0*H;
      #pragma unroll
      for (int f = 0; f < H; ++f) atomicAdd(&p[f], s[f]);
      atomicAdd(&gcnt[g0], 64.f);
    }
  } else if (valid){
    float* p = pooled + (size_t)g*H;
    #pragma unroll
    for (int f = 0; f < H; ++f) atomicAdd(&p[f], v[f]);
    atomicAdd(&gcnt[g], 1.f);
  }
}

// ---- D2RL head: one block of 512 threads (one per graph) ----
__device__ void block_stats16(const float* v, float* mu, float* rs,
                              float* wsum, float* wsq, int G){
  float s[H], q[H];
  #pragma unroll
  for (int f = 0; f < H; ++f){ s[f] = v[f]; q[f] = v[f]*v[f]; }
  for (int m = 1; m < 64; m <<= 1){
    #pragma unroll
    for (int f = 0; f < H; ++f){
      s[f] += __shfl_xor(s[f], m);
      q[f] += __shfl_xor(q[f], m);
    }
  }
  int wave = threadIdx.x >> 6, lane = threadIdx.x & 63;
  if (lane == 0){
    #pragma unroll
    for (int f = 0; f < H; ++f){ wsum[wave*H+f] = s[f]; wsq[wave*H+f] = q[f]; }
  }
  __syncthreads();
  int t = threadIdx.x;
  if (t < H){
    float S = 0.f, Q = 0.f;
    for (int w = 0; w < 8; ++w){ S += wsum[w*H+t]; Q += wsq[w*H+t]; }
    float m_ = S / (float)G;
    float var = Q / (float)G - m_*m_;
    mu[t] = m_;
    rs[t] = rsqrtf(var + 1e-5f);
  }
  __syncthreads();
}

__global__ __launch_bounds__(512) void k_head(const float* __restrict__ pooled, const float* __restrict__ gcnt,
    const float* __restrict__ g1, const float* __restrict__ be1,
    const float* __restrict__ Wl1, const float* __restrict__ bl1,
    const float* __restrict__ g2, const float* __restrict__ be2,
    const float* __restrict__ Wl2, const float* __restrict__ bl2,
    const float* __restrict__ g3, const float* __restrict__ be3,
    const float* __restrict__ Wl3, const float* __restrict__ bl3,
    const float* __restrict__ Wo, const float* __restrict__ bo,
    float* __restrict__ out, int G){
  __shared__ float wsum[8*H], wsq[8*H];
  __shared__ float pmu[H], prs[H], smu[H], srs[H];
  int g = threadIdx.x;
  float p[H];
  if (g < G){
    float c = fmaxf(gcnt[g], 1.f);
    #pragma unroll
    for (int f = 0; f < H; ++f) p[f] = pooled[(size_t)g*H+f] / c;
  } else {
    #pragma unroll
    for (int f = 0; f < H; ++f) p[f] = 0.f;
  }
  block_stats16(p, pmu, prs, wsum, wsq, G);
  float xn[H], z[H];
  #pragma unroll
  for (int f = 0; f < H; ++f) xn[f] = g1[f]*(p[f]-pmu[f])*prs[f] + be1[f];
  #pragma unroll
  for (int j = 0; j < H; ++j) z[j] = bl1[j];
  for (int k = 0; k < H; ++k){
    float xv = xn[k];
    #pragma unroll
    for (int j = 0; j < H; ++j) z[j] += xv * Wl1[k*H+j];
  }
  #pragma unroll
  for (int j = 0; j < H; ++j) z[j] = fmaxf(z[j], 0.f);
  block_stats16(z, smu, srs, wsum, wsq, G);
  float x2[2*H], z2[H];
  #pragma unroll
  for (int f = 0; f < H; ++f){
    x2[f]   = g2[f]  *(z[f]-smu[f])*srs[f] + be2[f];
    x2[H+f] = g2[H+f]*(p[f]-pmu[f])*prs[f] + be2[H+f];
  }
  #pragma unroll
  for (int j = 0; j < H; ++j) z2[j] = bl2[j];
  for (int k = 0; k < 2*H; ++k){
    float xv = x2[k];
    #pragma unroll
    for (int j = 0; j < H; ++j) z2[j] += xv * Wl2[k*H+j];
  }
  #pragma unroll
  for (int j = 0; j < H; ++j) z2[j] = fmaxf(z2[j], 0.f);
  block_stats16(z2, smu, srs, wsum, wsq, G);
  float x3[2*H], z3[H];
  #pragma unroll
  for (int f = 0; f < H; ++f){
    x3[f]   = g3[f]  *(z2[f]-smu[f])*srs[f] + be3[f];
    x3[H+f] = g3[H+f]*(p[f]-pmu[f])*prs[f] + be3[H+f];
  }
  #pragma unroll
  for (int j = 0; j < H; ++j) z3[j] = bl3[j];
  for (int k = 0; k < 2*H; ++k){
    float xv = x3[k];
    #pragma unroll
    for (int j = 0; j < H; ++j) z3[j] += xv * Wl3[k*H+j];
  }
  #pragma unroll
  for (int j = 0; j < H; ++j) z3[j] = fmaxf(z3[j], 0.f);
  if (g < G){
    float o = bo[0];
    #pragma unroll
    for (int j = 0; j < H; ++j) o += z3[j]*Wo[j];
    out[g] = o;
  }
}

extern "C" void kernel_launch(void* const* d_in, const int* in_sizes, int n_in,
                              void* d_out, int out_size, void* d_ws, size_t ws_size,
                              hipStream_t stream) {
  const float* x     = (const float*)d_in[0];
  const int*   ei    = (const int*)d_in[1];
  const float* attr  = (const float*)d_in[2];
  const int*   batch = (const int*)d_in[3];
  const float* W1  = (const float*)d_in[4];
  const float* We1 = (const float*)d_in[5];
  const float* as1 = (const float*)d_in[6];
  const float* ad1 = (const float*)d_in[7];
  const float* ae1 = (const float*)d_in[8];
  const float* b1  = (const float*)d_in[9];
  const float* bn1g = (const float*)d_in[10];
  const float* bn1b = (const float*)d_in[11];
  const float* W2  = (const float*)d_in[12];
  const float* We2 = (const float*)d_in[13];
  const float* as2 = (const float*)d_in[14];
  const float* ad2 = (const float*)d_in[15];
  const float* ae2 = (const float*)d_in[16];
  const float* b2  = (const float*)d_in[17];
  const float* bnl1g = (const float*)d_in[18];
  const float* bnl1b = (const float*)d_in[19];
  const float* Wl1 = (const float*)d_in[20];
  const float* bl1 = (const float*)d_in[21];
  const float* bnl2g = (const float*)d_in[22];
  const float* bnl2b = (const float*)d_in[23];
  const float* Wl2 = (const float*)d_in[24];
  const float* bl2 = (const float*)d_in[25];
  const float* bnl3g = (const float*)d_in[26];
  const float* bnl3b = (const float*)d_in[27];
  const float* Wl3 = (const float*)d_in[28];
  const float* bl3 = (const float*)d_in[29];
  const float* Wo  = (const float*)d_in[30];
  const float* bo  = (const float*)d_in[31];

  int N = in_sizes[0] / NF;
  int E = in_sizes[1] / 2;
  int G = out_size;
  const int* srcp = ei;
  const int* dstp = ei + E;

  int B     = (N + (1<<NSHIFT) - 1) >> NSHIFT;       // coarse buckets (147)
  int M     = B * NB;                                // count-matrix size (37632)
  int chunk = (E + NB - 1) / NB;                     // edges per binning block
  int nbN   = (N + TPB - 1)/TPB;
  int nbS   = (M + SBLK*SITEMS - 1)/(SBLK*SITEMS);   // scan blocks (74 <= 256)
  int nbG   = (N + (TPB/H) - 1)/(TPB/H);             // k_gat blocks (16 nodes/block)

  // ---- workspace layout ----
  // binned region (key 4B*E + dot2 8B*E = 57.6MB) is dead after k_csr;
  // A/Bv/asn/adn (20.4MB) alias on top of it.
  char* wsb = (char*)d_ws;
  int*    key  = (int*)wsb;                          // [0, 4E)
  float2* dot2 = (float2*)(wsb + (size_t)4*E);       // [4E, 12E)
  float* A   = (float*)wsb;                          // 16N floats (alias, post-CSR)
  float* Bv  = A  + (size_t)16*N;
  float* asn = Bv + (size_t)16*N;
  float* adn = asn + N;
  char* p = wsb + (size_t)12*E;
  int*   csr_src = (int*)p;   p += (size_t)4*E;
  float* dotA    = (float*)p; p += (size_t)4*E;
  float* dotB    = (float*)p; p += (size_t)4*E;
  int*   rowptr  = (int*)p;   p += (size_t)4*(N+1);
  int*   bbase   = (int*)p;   p += (size_t)4*(B+1);
  int*   cnt     = (int*)p;   p += (size_t)4*M;      // per-(bucket,block) counts -> bases
  int*   part    = (int*)p;   p += (size_t)4*256;
  float* par     = (float*)p; p += 4*64;             // [0..3]=wp [4..19]=scale [20..35]=shift
  float* pooled  = (float*)p; p += (size_t)4*G*H;
  float* gcnt    = (float*)p; p += (size_t)4*G;
  float* partial = (float*)p; p += (size_t)4*nbN*32;

  float* bnscale = par + 4;
  float* bnshift = par + 20;

  // zero-init (ws is re-poisoned 0xAA before every launch)
  hipMemsetAsync(pooled, 0, (size_t)(G*H + G)*sizeof(float), stream);

  k_prep<<<1, 64, 0, stream>>>(We1, ae1, We2, ae2, par);

  // ---- CSR build: coarse-bucket two-pass binning (no global atomics) ----
  k_bcount<<<NB, BTPB, 0, stream>>>(dstp, cnt, E, B, chunk);
  k_scan1<<<nbS, SBLK, 0, stream>>>(cnt, part, M);
  k_scan2<<<1, SBLK, 0, stream>>>(part, nbS, bbase, rowptr, B, N, E);
  k_scan3<<<nbS, SBLK, 0, stream>>>(cnt, part, bbase, M);
  k_bwrite<<<NB, BTPB, 0, stream>>>(srcp, dstp, attr, par, cnt, key, dot2, E, B, chunk);
  k_csr<<<B, 1024, 0, stream>>>(key, dot2, bbase, rowptr, csr_src, dotA, dotB, N);

  // ---- layer 1 ----
  k_node1<<<nbN, TPB, 0, stream>>>(x, W1, as1, ad1, A, asn, adn, N);
  k_gat<<<nbG, TPB, 0, stream>>>(rowptr, csr_src, dotA, asn, adn, A, b1, Bv, N);
  k_stats<<<nbN, TPB, 0, stream>>>(Bv, partial, N);
  k_bnprep<<<1, 256, 0, stream>>>(partial, nbN, bn1g, bn1b, bnscale, bnshift, N);

  // ---- layer 2 ----
  k_node2<<<nbN, TPB, 0, stream>>>(Bv, bnscale, bnshift, W2, as2, ad2, A, asn, adn, N);
  k_gat<<<nbG, TPB, 0, stream>>>(rowptr, csr_src, dotB, asn, adn, A, b2, Bv, N);

  // ---- pool + head ----
  k_pool<<<nbN, TPB, 0, stream>>>(Bv, batch, pooled, gcnt, N);
  k_head<<<1, 512, 0, stream>>>(pooled, gcnt, bnl1g, bnl1b, Wl1, bl1, bnl2g, bnl2b, Wl2, bl2,
                                bnl3g, bnl3b, Wl3, bl3, Wo, bo, (float*)d_out, G);
}

// Round 7
// 723.710 us; speedup vs baseline: 1.5490x; 1.0951x over previous
//
#include <hip/hip_runtime.h>
#include <hip/hip_fp16.h>
#include <math.h>

#define H 16
#define NF 64
#define TPB 256
#define NB 128        // binning blocks
#define BTPB 1024     // binning/gat threads per block
#define NSHIFT 6      // bucket = 64 consecutive dst nodes
#define MAXB 2560     // LDS counter capacity (B = ceil(150000/64) = 2344)
#define SBLK 256
#define SITEMS 8      // scan: 2048/block; M=2344*128=300032 -> 147 blocks <= 256
#define SRCMASK 0x3FFFF
#define CAP 3072      // bucket record capacity (avg 2048, Poisson tail << 3072)

__device__ __forceinline__ float lrelu(float v){ return v > 0.f ? v : 0.2f*v; }

// ---- derived edge-attention weights: par[0..1] = We1@ae1, par[2..3] = We2@ae2 ----
__global__ void k_prep(const float* __restrict__ We1, const float* __restrict__ ae1,
                       const float* __restrict__ We2, const float* __restrict__ ae2,
                       float* __restrict__ params){
  int t = threadIdx.x;
  if (t < 4){
    const float* We = (t < 2) ? We1 : We2;
    const float* ae = (t < 2) ? ae1 : ae2;
    int r = t & 1;
    float s = 0.f;
    for (int c = 0; c < H; ++c) s += We[r*H + c] * ae[c];
    params[t] = s;
  }
}

// ---- pass 1: per-(bucket, block) histogram in LDS ----
__global__ __launch_bounds__(BTPB) void k_bcount(const int* __restrict__ dst,
    int* __restrict__ cnt, int E, int B, int chunk){
  __shared__ int lcnt[MAXB];
  int blk = blockIdx.x, t = threadIdx.x;
  for (int i = t; i < B; i += BTPB) lcnt[i] = 0;
  __syncthreads();
  int e0 = blk*chunk, e1 = min(E, e0 + chunk);
  for (int e = e0 + t; e < e1; e += BTPB) atomicAdd(&lcnt[dst[e] >> NSHIFT], 1);
  __syncthreads();
  for (int i = t; i < B; i += BTPB) cnt[(size_t)i*NB + blk] = lcnt[i];
}

// ---- scan of the count matrix (bucket-major) -> exclusive ranges ----
__global__ __launch_bounds__(SBLK) void k_scan1(const int* __restrict__ cnt,
    int* __restrict__ part, int M){
  __shared__ int red[SBLK];
  int base = blockIdx.x*SBLK*SITEMS;
  int t = threadIdx.x;
  int s = 0;
  for (int i = 0; i < SITEMS; ++i){
    int idx = base + t*SITEMS + i;
    s += (idx < M) ? cnt[idx] : 0;
  }
  red[t] = s; __syncthreads();
  for (int off = SBLK/2; off > 0; off >>= 1){
    if (t < off) red[t] += red[t+off];
    __syncthreads();
  }
  if (t == 0) part[blockIdx.x] = red[0];
}

__global__ __launch_bounds__(SBLK) void k_scan2(int* __restrict__ part, int nb,
    int* __restrict__ bbase, int B, int E){
  __shared__ int sh[SBLK];
  int t = threadIdx.x;
  int v = (t < nb) ? part[t] : 0;
  sh[t] = v; __syncthreads();
  for (int off = 1; off < SBLK; off <<= 1){
    int add = (t >= off) ? sh[t-off] : 0;
    __syncthreads();
    sh[t] += add;
    __syncthreads();
  }
  if (t < nb) part[t] = sh[t] - v;   // exclusive block offsets
  if (t == 0) bbase[B] = E;
}

__global__ __launch_bounds__(SBLK) void k_scan3(int* __restrict__ cnt,
    const int* __restrict__ part, int* __restrict__ bbase, int M){
  __shared__ int sh[SBLK];
  int base = blockIdx.x*SBLK*SITEMS;
  int t = threadIdx.x;
  int loc[SITEMS]; int s = 0;
  for (int i = 0; i < SITEMS; ++i){
    int idx = base + t*SITEMS + i;
    loc[i] = s;
    s += (idx < M) ? cnt[idx] : 0;
  }
  sh[t] = s; __syncthreads();
  for (int off = 1; off < SBLK; off <<= 1){
    int add = (t >= off) ? sh[t-off] : 0;
    __syncthreads();
    sh[t] += add;
    __syncthreads();
  }
  int toff = sh[t] - s + part[blockIdx.x];
  for (int i = 0; i < SITEMS; ++i){
    int idx = base + t*SITEMS + i;
    if (idx < M){
      int excl = toff + loc[i];
      cnt[idx] = excl;                               // in-place per-(bucket,block) base
      if ((idx & (NB-1)) == 0) bbase[idx / NB] = excl;
    }
  }
}

// ---- pass 2: append 8B records {src|ldst<<18, half2(dot1,dot2)} into exclusive
//      ranges. Single region, frontier = 2344 lines/block x 16 blk/XCD = 2.4MB < L2. ----
__global__ __launch_bounds__(BTPB) void k_bwrite(const int* __restrict__ src,
    const int* __restrict__ dst, const float* __restrict__ attr, const float* __restrict__ wp,
    const int* __restrict__ base, int2* __restrict__ rec, int E, int B, int chunk){
  __shared__ int lcur[MAXB];
  int blk = blockIdx.x, t = threadIdx.x;
  for (int i = t; i < B; i += BTPB) lcur[i] = base[(size_t)i*NB + blk];
  __syncthreads();
  float w0 = wp[0], w1 = wp[1], w2 = wp[2], w3 = wp[3];
  int e0 = blk*chunk, e1 = min(E, e0 + chunk);
  for (int e = e0 + t; e < e1; e += BTPB){
    int d = dst[e];
    int b = d >> NSHIFT;
    float2 a = ((const float2*)attr)[e];
    __half h1 = __float2half_rn(a.x*w0 + a.y*w1);
    __half h2 = __float2half_rn(a.x*w2 + a.y*w3);
    unsigned u = (unsigned)__half_as_ushort(h1) | ((unsigned)__half_as_ushort(h2) << 16);
    int pos = atomicAdd(&lcur[b], 1);
    rec[pos] = make_int2(src[e] | ((d & 63) << 18), (int)u);
  }
}

// ---- fused GAT: per-bucket LDS sort + one-exp-per-edge + softmax aggregate ----
// 1024 threads = 64 nodes x 16 lanes (lane = feature).
template<int SEL>
__global__ __launch_bounds__(BTPB) void k_gatf(const int2* __restrict__ rec,
    const int* __restrict__ bbase, const float* __restrict__ asn, const float* __restrict__ adn,
    const float* __restrict__ h, const float* __restrict__ bias,
    float* __restrict__ out, int N){
  __shared__ int2 stage[CAP];
  __shared__ unsigned short sidx[CAP];
  __shared__ float wbuf[CAP];
  __shared__ int lcnt[64], lcur[64], sr[2];
  __shared__ float sadn[64], sbias[H];
  int b = blockIdx.x, t = threadIdx.x;
  int node0 = b << NSHIFT;
  if (t < 2) sr[t] = bbase[b + t];
  if (t < 64){
    lcnt[t] = 0;
    int nn = node0 + t;
    sadn[t] = (nn < N) ? adn[nn] : 0.f;
  }
  if (t >= 64 && t < 64 + H) sbias[t - 64] = bias[t - 64];
  __syncthreads();
  int r0 = sr[0], cnt = sr[1] - r0;
  // load + histogram
  for (int i = t; i < cnt; i += BTPB){
    int2 r = rec[r0 + i];
    stage[i] = r;
    atomicAdd(&lcnt[((unsigned)r.x) >> 18], 1);
  }
  __syncthreads();
  // exclusive scan over 64 node counters (wave 0)
  if (t < 64){
    int v = lcnt[t];
    int x = v;
    for (int o = 1; o < 64; o <<= 1){
      int y = __shfl_up(x, o);
      if (t >= o) x += y;
    }
    lcur[t] = x - v;
  }
  __syncthreads();
  // index sort + one exp per edge
  for (int i = t; i < cnt; i += BTPB){
    int2 r = stage[i];
    int ld = ((unsigned)r.x) >> 18;
    sidx[atomicAdd(&lcur[ld], 1)] = (unsigned short)i;
    unsigned u = (unsigned)r.y;
    float d = __half2float(__ushort_as_half((unsigned short)(SEL ? (u >> 16) : (u & 0xFFFFu))));
    wbuf[i] = __expf(lrelu(asn[r.x & SRCMASK] + sadn[ld] + d));
  }
  __syncthreads();
  int nl = t >> 4, lane = t & (H-1);
  int n = node0 + nl;
  if (n >= N) return;
  int deg = lcnt[nl];
  int s0 = lcur[nl] - deg;          // lcur advanced by deg during scatter
  float den = 0.f, acc = 0.f, sd = 0.f;
  for (int j = 0; j < deg; ++j){
    int ii = sidx[s0 + j];
    int2 r = stage[ii];
    float w = wbuf[ii];
    int s = r.x & SRCMASK;
    unsigned u = (unsigned)r.y;
    float d = __half2float(__ushort_as_half((unsigned short)(SEL ? (u >> 16) : (u & 0xFFFFu))));
    den += w; sd += d;
    acc += w * h[(size_t)s*H + lane];
  }
  // self-loop: edge_attr = mean of incoming attr -> dot = mean of incoming dots
  float lael = sd / fmaxf((float)deg, 1.f);
  float wl = __expf(lrelu(asn[n] + sadn[nl] + lael));
  den += wl;
  acc += wl * h[(size_t)n*H + lane];
  out[(size_t)n*H + lane] = fmaxf(acc/(den + 1e-16f) + sbias[lane], 0.f);
}

// ---- layer-1 node transform: h = x @ W1, alpha_src/dst ----
__global__ __launch_bounds__(TPB) void k_node1(const float* __restrict__ x, const float* __restrict__ W,
    const float* __restrict__ av_s, const float* __restrict__ av_d,
    float* __restrict__ hout, float* __restrict__ asn, float* __restrict__ adn, int N){
  __shared__ float sW[NF*H];
  __shared__ float sas[H], sad[H];
  int t = threadIdx.x;
  for (int i = t; i < NF*H; i += TPB) sW[i] = W[i];
  if (t < H){ sas[t] = av_s[t]; sad[t] = av_d[t]; }
  __syncthreads();
  int n = blockIdx.x*TPB + t;
  if (n >= N) return;
  float h[H];
  #pragma unroll
  for (int j = 0; j < H; ++j) h[j] = 0.f;
  const float4* xr = (const float4*)(x + (size_t)n*NF);
  #pragma unroll
  for (int k4 = 0; k4 < NF/4; ++k4){
    float4 xv = xr[k4];
    #pragma unroll
    for (int j = 0; j < H; ++j){
      h[j] += xv.x*sW[(4*k4+0)*H+j] + xv.y*sW[(4*k4+1)*H+j]
            + xv.z*sW[(4*k4+2)*H+j] + xv.w*sW[(4*k4+3)*H+j];
    }
  }
  float4* ho = (float4*)(hout + (size_t)n*H);
  ho[0] = make_float4(h[0],h[1],h[2],h[3]);
  ho[1] = make_float4(h[4],h[5],h[6],h[7]);
  ho[2] = make_float4(h[8],h[9],h[10],h[11]);
  ho[3] = make_float4(h[12],h[13],h[14],h[15]);
  float ss = 0.f, sd = 0.f;
  #pragma unroll
  for (int j = 0; j < H; ++j){ ss += h[j]*sas[j]; sd += h[j]*sad[j]; }
  asn[n] = ss; adn[n] = sd;
}

// ---- BN sum/sumsq: per-block partials, zero global atomics ----
__global__ __launch_bounds__(TPB) void k_stats(const float* __restrict__ B,
    float* __restrict__ partial, int N){
  __shared__ float lds[4][32];
  int t = threadIdx.x;
  int n = blockIdx.x*TPB + t;
  float v[H];
  if (n < N){
    const float4* br = (const float4*)(B + (size_t)n*H);
    float4 a0 = br[0], a1 = br[1], a2 = br[2], a3 = br[3];
    v[0]=a0.x; v[1]=a0.y; v[2]=a0.z; v[3]=a0.w;
    v[4]=a1.x; v[5]=a1.y; v[6]=a1.z; v[7]=a1.w;
    v[8]=a2.x; v[9]=a2.y; v[10]=a2.z; v[11]=a2.w;
    v[12]=a3.x; v[13]=a3.y; v[14]=a3.z; v[15]=a3.w;
  } else {
    #pragma unroll
    for (int f = 0; f < H; ++f) v[f] = 0.f;
  }
  float s[H], q[H];
  #pragma unroll
  for (int f = 0; f < H; ++f){ s[f] = v[f]; q[f] = v[f]*v[f]; }
  for (int m = 1; m < 64; m <<= 1){
    #pragma unroll
    for (int f = 0; f < H; ++f){
      s[f] += __shfl_xor(s[f], m);
      q[f] += __shfl_xor(q[f], m);
    }
  }
  int wave = t >> 6, lane = t & 63;
  if (lane == 0){
    #pragma unroll
    for (int f = 0; f < H; ++f){ lds[wave][f] = s[f]; lds[wave][H+f] = q[f]; }
  }
  __syncthreads();
  if (t < 32)
    partial[(size_t)blockIdx.x*32 + t] = lds[0][t] + lds[1][t] + lds[2][t] + lds[3][t];
}

// ---- final BN reduction over block partials + scale/shift ----
__global__ __launch_bounds__(256) void k_bnprep(const float* __restrict__ partial, int nb,
    const float* __restrict__ gamma, const float* __restrict__ beta,
    float* __restrict__ scale, float* __restrict__ shift, int N){
  __shared__ float red[256];
  __shared__ float tot[32];
  int t = threadIdx.x;
  int f = t & 31, c = t >> 5;        // 8 chunks x 32 features
  float s = 0.f;
  for (int b = c; b < nb; b += 8) s += partial[(size_t)b*32 + f];
  red[c*32 + f] = s;
  __syncthreads();
  if (t < 32){
    float S = 0.f;
    #pragma unroll
    for (int cc = 0; cc < 8; ++cc) S += red[cc*32 + t];
    tot[t] = S;
  }
  __syncthreads();
  if (t < H){
    float inv = 1.f / (float)N;
    float mu  = tot[t] * inv;
    float var = tot[H+t] * inv - mu*mu;
    float sc  = gamma[t] * rsqrtf(var + 1e-5f);
    scale[t] = sc;
    shift[t] = beta[t] - mu*sc;
  }
}

// ---- layer-2 node transform: BN + h = xn @ W2 + alphas ----
__global__ __launch_bounds__(TPB) void k_node2(const float* __restrict__ Bin, const float* __restrict__ scale,
    const float* __restrict__ shift, const float* __restrict__ W,
    const float* __restrict__ av_s, const float* __restrict__ av_d,
    float* __restrict__ hout, float* __restrict__ asn, float* __restrict__ adn, int N){
  __shared__ float sW[H*H];
  __shared__ float ssc[H], ssh[H], sas[H], sad[H];
  int t = threadIdx.x;
  if (t < H*H) sW[t] = W[t];
  if (t < H){ ssc[t] = scale[t]; ssh[t] = shift[t]; sas[t] = av_s[t]; sad[t] = av_d[t]; }
  __syncthreads();
  int n = blockIdx.x*TPB + t;
  if (n >= N) return;
  const float4* br = (const float4*)(Bin + (size_t)n*H);
  float4 a0 = br[0], a1 = br[1], a2 = br[2], a3 = br[3];
  float xn[H] = {a0.x,a0.y,a0.z,a0.w, a1.x,a1.y,a1.z,a1.w,
                 a2.x,a2.y,a2.z,a2.w, a3.x,a3.y,a3.z,a3.w};
  #pragma unroll
  for (int f = 0; f < H; ++f) xn[f] = xn[f]*ssc[f] + ssh[f];
  float h[H];
  #pragma unroll
  for (int j = 0; j < H; ++j) h[j] = 0.f;
  #pragma unroll
  for (int k = 0; k < H; ++k){
    float xv = xn[k];
    #pragma unroll
    for (int j = 0; j < H; ++j) h[j] += xv * sW[k*H+j];
  }
  float4* ho = (float4*)(hout + (size_t)n*H);
  ho[0] = make_float4(h[0],h[1],h[2],h[3]);
  ho[1] = make_float4(h[4],h[5],h[6],h[7]);
  ho[2] = make_float4(h[8],h[9],h[10],h[11]);
  ho[3] = make_float4(h[12],h[13],h[14],h[15]);
  float ss = 0.f, sd = 0.f;
  #pragma unroll
  for (int j = 0; j < H; ++j){ ss += h[j]*sas[j]; sd += h[j]*sad[j]; }
  asn[n] = ss; adn[n] = sd;
}

// ---- mean-pool accumulation; batch is sorted -> wave-uniform fast path ----
__global__ __launch_bounds__(TPB) void k_pool(const float* __restrict__ B,
    const int* __restrict__ batch, float* __restrict__ pooled, float* __restrict__ gcnt, int N){
  int n = blockIdx.x*TPB + threadIdx.x;
  int lane = threadIdx.x & 63;
  bool valid = n < N;
  int g = valid ? batch[n] : -1;
  float v[H];
  if (valid){
    const float4* br = (const float4*)(B + (size_t)n*H);
    float4 a0 = br[0], a1 = br[1], a2 = br[2], a3 = br[3];
    v[0]=a0.x; v[1]=a0.y; v[2]=a0.z; v[3]=a0.w;
    v[4]=a1.x; v[5]=a1.y; v[6]=a1.z; v[7]=a1.w;
    v[8]=a2.x; v[9]=a2.y; v[10]=a2.z; v[11]=a2.w;
    v[12]=a3.x; v[13]=a3.y; v[14]=a3.z; v[15]=a3.w;
  } else {
    #pragma unroll
    for (int f = 0; f < H; ++f) v[f] = 0.f;
  }
  int g0 = __shfl(g, 0);
  bool allsame = __all(valid && g == g0);
  if (allsame){
    float s[H];
    #pragma unroll
    for (int f = 0; f < H; ++f) s[f] = v[f];
    for (int m = 1; m < 64; m <<= 1){
      #pragma unroll
      for (int f = 0; f < H; ++f) s[f] += __shfl_xor(s[f], m);
    }
    if (lane == 0){
      float* p = pooled + (size_t)g0*H;
      #pragma unroll
      for (int f = 0; f < H; ++f) atomicAdd(&p[f], s[f]);
      atomicAdd(&gcnt[g0], 64.f);
    }
  } else if (valid){
    float* p = pooled + (size_t)g*H;
    #pragma unroll
    for (int f = 0; f < H; ++f) atomicAdd(&p[f], v[f]);
    atomicAdd(&gcnt[g], 1.f);
  }
}

// ---- D2RL head: one block of 512 threads (one per graph) ----
__device__ void block_stats16(const float* v, float* mu, float* rs,
                              float* wsum, float* wsq, int G){
  float s[H], q[H];
  #pragma unroll
  for (int f = 0; f < H; ++f){ s[f] = v[f]; q[f] = v[f]*v[f]; }
  for (int m = 1; m < 64; m <<= 1){
    #pragma unroll
    for (int f = 0; f < H; ++f){
      s[f] += __shfl_xor(s[f], m);
      q[f] += __shfl_xor(q[f], m);
    }
  }
  int wave = threadIdx.x >> 6, lane = threadIdx.x & 63;
  if (lane == 0){
    #pragma unroll
    for (int f = 0; f < H; ++f){ wsum[wave*H+f] = s[f]; wsq[wave*H+f] = q[f]; }
  }
  __syncthreads();
  int t = threadIdx.x;
  if (t < H){
    float S = 0.f, Q = 0.f;
    for (int w = 0; w < 8; ++w){ S += wsum[w*H+t]; Q += wsq[w*H+t]; }
    float m_ = S / (float)G;
    float var = Q / (float)G - m_*m_;
    mu[t] = m_;
    rs[t] = rsqrtf(var + 1e-5f);
  }
  __syncthreads();
}

__global__ __launch_bounds__(512) void k_head(const float* __restrict__ pooled, const float* __restrict__ gcnt,
    const float* __restrict__ g1, const float* __restrict__ be1,
    const float* __restrict__ Wl1, const float* __restrict__ bl1,
    const float* __restrict__ g2, const float* __restrict__ be2,
    const float* __restrict__ Wl2, const float* __restrict__ bl2,
    const float* __restrict__ g3, const float* __restrict__ be3,
    const float* __restrict__ Wl3, const float* __restrict__ bl3,
    const float* __restrict__ Wo, const float* __restrict__ bo,
    float* __restrict__ out, int G){
  __shared__ float wsum[8*H], wsq[8*H];
  __shared__ float pmu[H], prs[H], smu[H], srs[H];
  int g = threadIdx.x;
  float p[H];
  if (g < G){
    float c = fmaxf(gcnt[g], 1.f);
    #pragma unroll
    for (int f = 0; f < H; ++f) p[f] = pooled[(size_t)g*H+f] / c;
  } else {
    #pragma unroll
    for (int f = 0; f < H; ++f) p[f] = 0.f;
  }
  block_stats16(p, pmu, prs, wsum, wsq, G);
  float xn[H], z[H];
  #pragma unroll
  for (int f = 0; f < H; ++f) xn[f] = g1[f]*(p[f]-pmu[f])*prs[f] + be1[f];
  #pragma unroll
  for (int j = 0; j < H; ++j) z[j] = bl1[j];
  for (int k = 0; k < H; ++k){
    float xv = xn[k];
    #pragma unroll
    for (int j = 0; j < H; ++j) z[j] += xv * Wl1[k*H+j];
  }
  #pragma unroll
  for (int j = 0; j < H; ++j) z[j] = fmaxf(z[j], 0.f);
  block_stats16(z, smu, srs, wsum, wsq, G);
  float x2[2*H], z2[H];
  #pragma unroll
  for (int f = 0; f < H; ++f){
    x2[f]   = g2[f]  *(z[f]-smu[f])*srs[f] + be2[f];
    x2[H+f] = g2[H+f]*(p[f]-pmu[f])*prs[f] + be2[H+f];
  }
  #pragma unroll
  for (int j = 0; j < H; ++j) z2[j] = bl2[j];
  for (int k = 0; k < 2*H; ++k){
    float xv = x2[k];
    #pragma unroll
    for (int j = 0; j < H; ++j) z2[j] += xv * Wl2[k*H+j];
  }
  #pragma unroll
  for (int j = 0; j < H; ++j) z2[j] = fmaxf(z2[j], 0.f);
  block_stats16(z2, smu, srs, wsum, wsq, G);
  float x3[2*H], z3[H];
  #pragma unroll
  for (int f = 0; f < H; ++f){
    x3[f]   = g3[f]  *(z2[f]-smu[f])*srs[f] + be3[f];
    x3[H+f] = g3[H+f]*(p[f]-pmu[f])*prs[f] + be3[H+f];
  }
  #pragma unroll
  for (int j = 0; j < H; ++j) z3[j] = bl3[j];
  for (int k = 0; k < 2*H; ++k){
    float xv = x3[k];
    #pragma unroll
    for (int j = 0; j < H; ++j) z3[j] += xv * Wl3[k*H+j];
  }
  #pragma unroll
  for (int j = 0; j < H; ++j) z3[j] = fmaxf(z3[j], 0.f);
  if (g < G){
    float o = bo[0];
    #pragma unroll
    for (int j = 0; j < H; ++j) o += z3[j]*Wo[j];
    out[g] = o;
  }
}

extern "C" void kernel_launch(void* const* d_in, const int* in_sizes, int n_in,
                              void* d_out, int out_size, void* d_ws, size_t ws_size,
                              hipStream_t stream) {
  const float* x     = (const float*)d_in[0];
  const int*   ei    = (const int*)d_in[1];
  const float* attr  = (const float*)d_in[2];
  const int*   batch = (const int*)d_in[3];
  const float* W1  = (const float*)d_in[4];
  const float* We1 = (const float*)d_in[5];
  const float* as1 = (const float*)d_in[6];
  const float* ad1 = (const float*)d_in[7];
  const float* ae1 = (const float*)d_in[8];
  const float* b1  = (const float*)d_in[9];
  const float* bn1g = (const float*)d_in[10];
  const float* bn1b = (const float*)d_in[11];
  const float* W2  = (const float*)d_in[12];
  const float* We2 = (const float*)d_in[13];
  const float* as2 = (const float*)d_in[14];
  const float* ad2 = (const float*)d_in[15];
  const float* ae2 = (const float*)d_in[16];
  const float* b2  = (const float*)d_in[17];
  const float* bnl1g = (const float*)d_in[18];
  const float* bnl1b = (const float*)d_in[19];
  const float* Wl1 = (const float*)d_in[20];
  const float* bl1 = (const float*)d_in[21];
  const float* bnl2g = (const float*)d_in[22];
  const float* bnl2b = (const float*)d_in[23];
  const float* Wl2 = (const float*)d_in[24];
  const float* bl2 = (const float*)d_in[25];
  const float* bnl3g = (const float*)d_in[26];
  const float* bnl3b = (const float*)d_in[27];
  const float* Wl3 = (const float*)d_in[28];
  const float* bl3 = (const float*)d_in[29];
  const float* Wo  = (const float*)d_in[30];
  const float* bo  = (const float*)d_in[31];

  int N = in_sizes[0] / NF;
  int E = in_sizes[1] / 2;
  int G = out_size;
  const int* srcp = ei;
  const int* dstp = ei + E;

  int B     = (N + 63) >> 6;                         // 64-node buckets (2344)
  int M     = B * NB;                                // count-matrix size (300032)
  int chunk = (E + NB - 1) / NB;                     // edges per binning block
  int nbN   = (N + TPB - 1)/TPB;
  int nbS   = (M + SBLK*SITEMS - 1)/(SBLK*SITEMS);   // scan blocks (147 <= 256)

  // ---- workspace layout (rec persists through both GAT layers; no aliasing) ----
  char* wsb = (char*)d_ws;
  int2*  rec = (int2*)wsb;                           // 8B * E
  char* p = wsb + (size_t)8*E;
  float* A   = (float*)p;     p += (size_t)16*N*4;   // h (current layer)
  float* Bv  = (float*)p;     p += (size_t)16*N*4;   // layer output
  float* asn = (float*)p;     p += (size_t)N*4;
  float* adn = (float*)p;     p += (size_t)N*4;
  int*   cnt     = (int*)p;   p += (size_t)4*M;      // per-(bucket,block) counts -> bases
  int*   bbase   = (int*)p;   p += (size_t)4*(B+1);
  int*   part    = (int*)p;   p += (size_t)4*256;
  float* par     = (float*)p; p += 4*64;             // [0..3]=wp [4..19]=scale [20..35]=shift
  float* pooled  = (float*)p; p += (size_t)4*G*H;
  float* gcnt    = (float*)p; p += (size_t)4*G;
  float* partial = (float*)p; p += (size_t)4*nbN*32;

  float* bnscale = par + 4;
  float* bnshift = par + 20;

  // zero-init (ws is re-poisoned 0xAA before every launch)
  hipMemsetAsync(pooled, 0, (size_t)(G*H + G)*sizeof(float), stream);

  k_prep<<<1, 64, 0, stream>>>(We1, ae1, We2, ae2, par);

  // ---- binning: two-pass exclusive-range, 8B records, no global atomics ----
  k_bcount<<<NB, BTPB, 0, stream>>>(dstp, cnt, E, B, chunk);
  k_scan1<<<nbS, SBLK, 0, stream>>>(cnt, part, M);
  k_scan2<<<1, SBLK, 0, stream>>>(part, nbS, bbase, B, E);
  k_scan3<<<nbS, SBLK, 0, stream>>>(cnt, part, bbase, M);
  k_bwrite<<<NB, BTPB, 0, stream>>>(srcp, dstp, attr, par, cnt, rec, E, B, chunk);

  // ---- layer 1 ----
  k_node1<<<nbN, TPB, 0, stream>>>(x, W1, as1, ad1, A, asn, adn, N);
  k_gatf<0><<<B, BTPB, 0, stream>>>(rec, bbase, asn, adn, A, b1, Bv, N);
  k_stats<<<nbN, TPB, 0, stream>>>(Bv, partial, N);
  k_bnprep<<<1, 256, 0, stream>>>(partial, nbN, bn1g, bn1b, bnscale, bnshift, N);

  // ---- layer 2 ----
  k_node2<<<nbN, TPB, 0, stream>>>(Bv, bnscale, bnshift, W2, as2, ad2, A, asn, adn, N);
  k_gatf<1><<<B, BTPB, 0, stream>>>(rec, bbase, asn, adn, A, b2, Bv, N);

  // ---- pool + head ----
  k_pool<<<nbN, TPB, 0, stream>>>(Bv, batch, pooled, gcnt, N);
  k_head<<<1, 512, 0, stream>>>(pooled, gcnt, bnl1g, bnl1b, Wl1, bl1, bnl2g, bnl2b, Wl2, bl2,
                                bnl3g, bnl3b, Wl3, bl3, Wo, bo, (float*)d_out, G);
}